// Round 8
// baseline (658.186 us; speedup 1.0000x reference)
//
#include <hip/hip_runtime.h>
#include <hip/hip_fp16.h>
#include <math.h>

// ---------------------------------------------------------------------------
// GaussianGAT forward: binned CSR build, hierarchical degree sort (descending
// LPT, locality-preserving within bins), branch-split packed-fp16 GATv2
// aggregation (pipelined gathers, DPP score reduce, fused lrelu/exp2),
// fp16 inter-level buffers, W-amortized MFMA transforms (multi-tile waves),
// reparam+pool fused into the level-2 aggregate epilogue, FC head.
// 15 dispatches.
// ---------------------------------------------------------------------------

#define BSH 7                 // bucket = dst >> BSH (128 nodes / bucket)
#define BMSK ((1 << BSH) - 1)
#define CHUNK 4096            // edges per binfill block
#define SNB 4096              // nodes per degree-sort block

typedef _Float16 h2 __attribute__((ext_vector_type(2)));
typedef _Float16 h8 __attribute__((ext_vector_type(8)));
typedef float f4 __attribute__((ext_vector_type(4)));

__device__ __forceinline__ float elu1(float v) {
    return v > 0.f ? v : (__expf(v) - 1.f);
}

// 2^x via hardware v_exp_f32 (builtin so the compiler manages trans-op hazards)
__device__ __forceinline__ float exp2fast(float x) {
#if defined(__has_builtin)
#if __has_builtin(__builtin_amdgcn_exp2f)
    return __builtin_amdgcn_exp2f(x);
#else
    return exp2f(x);
#endif
#else
    return exp2f(x);
#endif
}

// f32 += dot(h2, h2) with f32 accumulation (v_dot2_f32_f16)
__device__ __forceinline__ float dot2f(h2 a, h2 b, float c) {
#if defined(__has_builtin)
#if __has_builtin(__builtin_amdgcn_fdot2)
    return __builtin_amdgcn_fdot2(a, b, c, false);
#else
    return fmaf((float)a.x, (float)b.x, fmaf((float)a.y, (float)b.y, c));
#endif
#else
    return fmaf((float)a.x, (float)b.x, fmaf((float)a.y, (float)b.y, c));
#endif
}

// cross-lane permuted copy via DPP (row-aligned 16-lane groups)
template <int CTRL>
__device__ __forceinline__ float dppf(float v) {
    int r = __builtin_amdgcn_update_dpp(0, __builtin_bit_cast(int, v), CTRL, 0xF, 0xF, true);
    return __builtin_bit_cast(float, r);
}

// ---- CSR build -------------------------------------------------------------

__global__ void k_hist_bucket(const int* __restrict__ dst, int E,
                              int* __restrict__ bcnt, int nbk) {
    __shared__ int h[1024];
    for (int i = threadIdx.x; i < 1024; i += blockDim.x) h[i] = 0;
    __syncthreads();
    int stride = gridDim.x * blockDim.x;
    for (int e = blockIdx.x * blockDim.x + threadIdx.x; e < E; e += stride)
        atomicAdd(&h[dst[e] >> BSH], 1);
    __syncthreads();
    for (int i = threadIdx.x; i < nbk; i += blockDim.x)
        if (h[i]) atomicAdd(&bcnt[i], h[i]);
}

// scan buckets; also zero bfill + bin_cnt (saves two memset dispatches)
__global__ void k_scan_buckets(const int* __restrict__ bcnt, int nbk, int* __restrict__ boff,
                               int* __restrict__ bfill, int* __restrict__ bin_cnt) {
    __shared__ int sh[1024];
    int t = threadIdx.x;
    if (t < nbk) bfill[t] = 0;
    if (t < 256) bin_cnt[t] = 0;
    int v = (t < nbk) ? bcnt[t] : 0;
    sh[t] = v;
    __syncthreads();
    for (int o = 1; o < 1024; o <<= 1) {
        int u = (t >= o) ? sh[t - o] : 0;
        __syncthreads();
        sh[t] += u;
        __syncthreads();
    }
    if (t < nbk) boff[t] = sh[t] - v;
    if (t == nbk - 1) boff[nbk] = sh[t];
}

__global__ __launch_bounds__(256) void k_binfill(
    const int* __restrict__ src, const int* __restrict__ dst, int E,
    const int* __restrict__ boff, int* __restrict__ bfill, int* __restrict__ pairs) {
    __shared__ int h[1024];
    __shared__ int sbase[1024];
    int c0 = blockIdx.x * CHUNK;
    int c1 = min(c0 + CHUNK, E);
    for (int i = threadIdx.x; i < 1024; i += 256) h[i] = 0;
    __syncthreads();
    for (int e = c0 + threadIdx.x; e < c1; e += 256)
        atomicAdd(&h[dst[e] >> BSH], 1);
    __syncthreads();
    for (int i = threadIdx.x; i < 1024; i += 256) {
        int c = h[i];
        sbase[i] = c ? (boff[i] + atomicAdd(&bfill[i], c)) : 0;
        h[i] = 0;
    }
    __syncthreads();
    for (int e = c0 + threadIdx.x; e < c1; e += 256) {
        int d = dst[e];
        int b = d >> BSH;
        int off = atomicAdd(&h[b], 1);
        pairs[sbase[b] + off] = (src[e] << BSH) | (d & BMSK);
    }
}

__global__ __launch_bounds__(256) void k_bucket_csr(
    const int* __restrict__ pairs, const int* __restrict__ boff,
    int* __restrict__ rowptr, int* __restrict__ col, int N, int E) {
    __shared__ int deg[128], fill[128], scan[128], base[128];
    int b = blockIdx.x;
    int e0 = boff[b], e1 = boff[b + 1];
    int t = threadIdx.x;
    if (t < 128) { deg[t] = 0; fill[t] = 0; }
    __syncthreads();
    for (int i = e0 + t; i < e1; i += 256)
        atomicAdd(&deg[pairs[i] & BMSK], 1);
    __syncthreads();
    if (t < 128) scan[t] = deg[t];
    __syncthreads();
    for (int o = 1; o < 128; o <<= 1) {
        int u = (t >= o && t < 128) ? scan[t - o] : 0;
        __syncthreads();
        if (t < 128) scan[t] += u;
        __syncthreads();
    }
    if (t < 128) {
        int excl = e0 + scan[t] - deg[t];
        int node = (b << BSH) + t;
        if (node < N) rowptr[node] = excl;
        if (node == N - 1) rowptr[N] = E;
        base[t] = excl;
    }
    __syncthreads();
    for (int i = e0 + t; i < e1; i += 256) {
        int pk = pairs[i];
        int d = pk & BMSK;
        int pos = base[d] + atomicAdd(&fill[d], 1);
        col[pos] = ((unsigned)pk) >> BSH;
    }
}

// ---- degree counting-sort (hierarchical, contention-free, LOCALITY-KEEPING) --
// Key is 255 - min(deg,255): DESCENDING degree (LPT schedule, short tail).
// The blk_base two-pass scheme keeps ascending node-ID runs within each bin —
// this ordering is what makes aggregate reads/writes coalesce (R5 lesson:
// a global-ticket sort randomized within-bin order and cost 2x total time).

__global__ __launch_bounds__(256) void k_deg_hist(const int* __restrict__ rowptr, int n,
                                                  int* __restrict__ bin_cnt,
                                                  int* __restrict__ blk_base) {
    __shared__ int h[256];
    h[threadIdx.x] = 0;
    __syncthreads();
    int b0 = blockIdx.x * SNB;
    int b1 = min(b0 + SNB, n);
    for (int i = b0 + threadIdx.x; i < b1; i += 256) {
        int d = 255 - min(rowptr[i + 1] - rowptr[i], 255);
        atomicAdd(&h[d], 1);
    }
    __syncthreads();
    int c = h[threadIdx.x];
    blk_base[blockIdx.x * 256 + threadIdx.x] = c ? atomicAdd(&bin_cnt[threadIdx.x], c) : 0;
}

// scan 256 degree bins; also zero zsum (saves a memset dispatch)
__global__ void k_scan256(const int* __restrict__ bin_cnt, int* __restrict__ bin_off,
                          float* __restrict__ zsum, int G) {
    __shared__ int sh[256];
    int t = threadIdx.x;
    for (int i = t; i < G * 64; i += 256) zsum[i] = 0.f;
    int v = bin_cnt[t];
    sh[t] = v;
    __syncthreads();
    for (int o = 1; o < 256; o <<= 1) {
        int u = (t >= o) ? sh[t - o] : 0;
        __syncthreads();
        sh[t] += u;
        __syncthreads();
    }
    bin_off[t] = sh[t] - v;
}

__global__ __launch_bounds__(256) void k_deg_scatter(const int* __restrict__ rowptr, int n,
                                                     const int* __restrict__ bin_off,
                                                     const int* __restrict__ blk_base,
                                                     int* __restrict__ nodeof) {
    __shared__ int h[256];
    h[threadIdx.x] = 0;
    __syncthreads();
    int b0 = blockIdx.x * SNB;
    int b1 = min(b0 + SNB, n);
    for (int i = b0 + threadIdx.x; i < b1; i += 256) {
        int d = 255 - min(rowptr[i + 1] - rowptr[i], 255);
        int my = atomicAdd(&h[d], 1);
        nodeof[bin_off[d] + blk_base[blockIdx.x * 256 + d] + my] = i;
    }
}

// ---- node transforms -------------------------------------------------------

// level 0, both branches fused: X [n,7] -> xlb/xrb [n,128]
__global__ void k_transform7(const float* __restrict__ X,
                             const float* __restrict__ mWl, const float* __restrict__ mbl,
                             const float* __restrict__ mWr, const float* __restrict__ mbr,
                             const float* __restrict__ vWl, const float* __restrict__ vbl,
                             const float* __restrict__ vWr, const float* __restrict__ vbr,
                             __half* __restrict__ xlb, __half* __restrict__ xrb, int n) {
    int t = blockIdx.x * blockDim.x + threadIdx.x;
    int node = t >> 6;
    if (node >= n) return;
    int h = t & 63;
    float aml = mbl[h], amr = mbr[h], avl = vbl[h], avr = vbr[h];
#pragma unroll
    for (int k = 0; k < 7; ++k) {
        float xv = X[node * 7 + k];
        aml = fmaf(xv, mWl[h * 7 + k], aml);
        amr = fmaf(xv, mWr[h * 7 + k], amr);
        avl = fmaf(xv, vWl[h * 7 + k], avl);
        avr = fmaf(xv, vWr[h * 7 + k], avr);
    }
    size_t o = (size_t)node * 128;
    xlb[o + h] = __float2half(aml);
    xlb[o + 64 + h] = __float2half(avl);
    xrb[o + h] = __float2half(amr);
    xrb[o + 64 + h] = __float2half(avr);
}

// hidden levels via MFMA: out.T = W @ x.T   (M=channel, N=node, K=64)
// blockIdx.y: 0 = mean branch (base 0), 1 = logvar branch (base 64).
// Inputs are fp16 [n,64]. Grid is sized so each wave sweeps ~4 tiles,
// amortizing the 16KB/wave W-fragment load (was 1 tile/wave = 4x the
// L2 weight traffic of the features themselves).
__global__ __launch_bounds__(256) void k_transform_mfma2(
    const __half* __restrict__ Xm, const __half* __restrict__ Xv,
    const float* __restrict__ mWl, const float* __restrict__ mbl,
    const float* __restrict__ mWr, const float* __restrict__ mbr,
    const float* __restrict__ vWl, const float* __restrict__ vbl,
    const float* __restrict__ vWr, const float* __restrict__ vbr,
    __half* __restrict__ xlb, __half* __restrict__ xrb, int n) {
    int brn = blockIdx.y;
    const __half* X = brn ? Xv : Xm;
    const float* Wl = brn ? vWl : mWl;
    const float* bl = brn ? vbl : mbl;
    const float* Wr = brn ? vWr : mWr;
    const float* br = brn ? vbr : mbr;
    int base = brn * 64;

    __shared__ float biasLds[128];
    {
        int t = threadIdx.x;
        if (t < 64) biasLds[t] = bl[t];
        else if (t < 128) biasLds[t] = br[t - 64];
    }
    __syncthreads();
    int lane = threadIdx.x & 63;
    int l16 = lane & 15, lhi = lane >> 4;

    h8 aW[2][8];
    const float* Wp0 = Wl + (size_t)l16 * 64 + lhi * 8;
    const float* Wp1 = Wr + (size_t)l16 * 64 + lhi * 8;
#pragma unroll
    for (int tl = 0; tl < 4; ++tl) {
#pragma unroll
        for (int c = 0; c < 2; ++c) {
            const float* p0 = Wp0 + (size_t)tl * 16 * 64 + c * 32;
            const float* p1 = Wp1 + (size_t)tl * 16 * 64 + c * 32;
            float4 u0 = *(const float4*)p0, u1 = *(const float4*)(p0 + 4);
            float4 v0 = *(const float4*)p1, v1 = *(const float4*)(p1 + 4);
            h8 a0 = {(_Float16)u0.x, (_Float16)u0.y, (_Float16)u0.z, (_Float16)u0.w,
                     (_Float16)u1.x, (_Float16)u1.y, (_Float16)u1.z, (_Float16)u1.w};
            h8 a1 = {(_Float16)v0.x, (_Float16)v0.y, (_Float16)v0.z, (_Float16)v0.w,
                     (_Float16)v1.x, (_Float16)v1.y, (_Float16)v1.z, (_Float16)v1.w};
            aW[0][tl * 2 + c] = a0;
            aW[1][tl * 2 + c] = a1;
        }
    }

    int ntiles = (n + 15) >> 4;
    int wtile = blockIdx.x * 4 + (threadIdx.x >> 6);
    int wstride = gridDim.x * 4;
    for (int tile = wtile; tile < ntiles; tile += wstride) {
        int nb = tile * 16;
        int node = nb + l16;
        int nload = min(node, n - 1);
        h8 Bf[2];
#pragma unroll
        for (int c = 0; c < 2; ++c) {
            const __half* p = X + (size_t)nload * 64 + c * 32 + lhi * 8;
            Bf[c] = *(const h8*)p;
        }
        f4 acc[2][4];
#pragma unroll
        for (int m = 0; m < 2; ++m)
#pragma unroll
            for (int tl = 0; tl < 4; ++tl) {
                f4 a = {0.f, 0.f, 0.f, 0.f};
                a = __builtin_amdgcn_mfma_f32_16x16x32_f16(aW[m][tl * 2 + 0], Bf[0], a, 0, 0, 0);
                a = __builtin_amdgcn_mfma_f32_16x16x32_f16(aW[m][tl * 2 + 1], Bf[1], a, 0, 0, 0);
                acc[m][tl] = a;
            }
        if (node < n) {
#pragma unroll
            for (int m = 0; m < 2; ++m) {
                __half* op = (m ? xrb : xlb) + (size_t)node * 128 + base;
#pragma unroll
                for (int tl = 0; tl < 4; ++tl) {
                    float4 bb = *(const float4*)&biasLds[m * 64 + tl * 16 + 4 * lhi];
                    h2 lo = {(_Float16)(acc[m][tl][0] + bb.x), (_Float16)(acc[m][tl][1] + bb.y)};
                    h2 hi = {(_Float16)(acc[m][tl][2] + bb.z), (_Float16)(acc[m][tl][3] + bb.w)};
                    uint2 pk = {*(unsigned*)&lo, *(unsigned*)&hi};
                    *(uint2*)(op + tl * 16 + 4 * lhi) = pk;
                }
            }
        }
    }
}

// ---- fused dual-branch GATv2 aggregation: branch-split lanes ---------------
// 16 lanes per dst node; lanes 0-7 own mean ch [8s..8s+8), lanes 8-15 logvar.
// Score: att·lrelu(y) = (0.6*log2e*att)·y + (0.4*log2e*att)·|y|, two
// v_dot2_f32_f16 chains, DPP butterfly reduce, exp2 via builtin.
// Gathers double-buffered (depth 4), col indices prefetched 2 blocks ahead.
// xlb row = 128 halves = 256 B = 16 int4 — row stride in int4 is 16.
// HOUT: write fp16 inter-level buffers. FUSE (level 2): write f32 outputs
// AND do reparam+pool in the epilogue (replaces the k_zpool pass; fusion
// verified correct in R5, cost there was the broken sort, not this).

template <bool HOUT, bool FUSE>
__global__ __launch_bounds__(256) void k_aggregate2(
    const __half* __restrict__ xlb, const __half* __restrict__ xrb,
    const float* __restrict__ attm, const float* __restrict__ attv,
    const float* __restrict__ biasm, const float* __restrict__ biasv,
    const int* __restrict__ rowptr, const int* __restrict__ col,
    const int* __restrict__ nodeof,
    void* __restrict__ outm, void* __restrict__ outv, int n,
    const float* __restrict__ eps, const int* __restrict__ batch,
    float* __restrict__ zsum) {
    int t = blockIdx.x * blockDim.x + threadIdx.x;
    int gid = t >> 4;
    if (gid >= n) return;
    int node = nodeof[gid];
    int l = t & 15;
    int s = l & 7;
    bool isv = l >= 8;

    // my 8 channels of my branch (xlb layout = [mean64|logvar64])
    int4 xri = ((const int4*)(xrb + (size_t)node * 128))[l];
    h2 xr0 = *(h2*)&xri.x, xr1 = *(h2*)&xri.y, xr2 = *(h2*)&xri.z, xr3 = *(h2*)&xri.w;
    const float* ap = (isv ? attv : attm) + s * 8;
    float4 af0 = *(const float4*)ap, af1 = *(const float4*)(ap + 4);
    const float C6 = 0.6f * 1.44269504f;      // fold lrelu + log2(e) for exp2
    const float C4 = 0.4f * 1.44269504f;
    h2 a6_0 = {(_Float16)(af0.x * C6), (_Float16)(af0.y * C6)};
    h2 a6_1 = {(_Float16)(af0.z * C6), (_Float16)(af0.w * C6)};
    h2 a6_2 = {(_Float16)(af1.x * C6), (_Float16)(af1.y * C6)};
    h2 a6_3 = {(_Float16)(af1.z * C6), (_Float16)(af1.w * C6)};
    h2 a4_0 = {(_Float16)(af0.x * C4), (_Float16)(af0.y * C4)};
    h2 a4_1 = {(_Float16)(af0.z * C4), (_Float16)(af0.w * C4)};
    h2 a4_2 = {(_Float16)(af1.x * C4), (_Float16)(af1.y * C4)};
    h2 a4_3 = {(_Float16)(af1.z * C4), (_Float16)(af1.w * C4)};

    float ac0 = 0.f, ac1 = 0.f, ac2 = 0.f, ac3 = 0.f;
    float ac4 = 0.f, ac5 = 0.f, ac6 = 0.f, ac7 = 0.f;
    float ssum = 0.f;

    auto proc = [&](int4 qi) {
        h2 x0 = *(h2*)&qi.x, x1 = *(h2*)&qi.y, x2 = *(h2*)&qi.z, x3 = *(h2*)&qi.w;
        h2 y0 = x0 + xr0, y1 = x1 + xr1, y2 = x2 + xr2, y3 = x3 + xr3;
        int z0i = (*(int*)&y0) & 0x7FFF7FFF;
        int z1i = (*(int*)&y1) & 0x7FFF7FFF;
        int z2i = (*(int*)&y2) & 0x7FFF7FFF;
        int z3i = (*(int*)&y3) & 0x7FFF7FFF;
        h2 z0 = *(h2*)&z0i, z1 = *(h2*)&z1i, z2 = *(h2*)&z2i, z3 = *(h2*)&z3i;
        float sc = dot2f(y0, a6_0, 0.f);
        float sa = dot2f(z0, a4_0, 0.f);
        sc = dot2f(y1, a6_1, sc);
        sa = dot2f(z1, a4_1, sa);
        sc = dot2f(y2, a6_2, sc);
        sa = dot2f(z2, a4_2, sa);
        sc = dot2f(y3, a6_3, sc);
        sa = dot2f(z3, a4_3, sa);
        sc += sa;
        sc += dppf<0xB1>(sc);             // xor 1 (quad_perm 1,0,3,2)
        sc += dppf<0x4E>(sc);             // xor 2 (quad_perm 2,3,0,1)
        sc += dppf<0x141>(sc);            // xor 4 (row_half_mirror)
        float w = exp2fast(sc);           // 2^sc (log2e folded into att)
        ssum += w;
        ac0 = fmaf(w, (float)x0.x, ac0);
        ac1 = fmaf(w, (float)x0.y, ac1);
        ac2 = fmaf(w, (float)x1.x, ac2);
        ac3 = fmaf(w, (float)x1.y, ac3);
        ac4 = fmaf(w, (float)x2.x, ac4);
        ac5 = fmaf(w, (float)x2.y, ac5);
        ac6 = fmaf(w, (float)x3.x, ac6);
        ac7 = fmaf(w, (float)x3.y, ac7);
    };

    int r0 = rowptr[node], r1 = rowptr[node + 1];
    const int4* xp = (const int4*)xlb + l;     // row stride = 16 int4 (256 B)
    int last = r1 - 1;
    int nb = (r1 - r0) >> 2;
    int e = r0;
    int t0 = 0, t1 = 0, t2 = 0, t3 = 0;
    int4 qA0, qA1, qA2, qA3;
    if (nb) {
        int s0 = col[e], s1 = col[e + 1], s2 = col[e + 2], s3 = col[e + 3];
        qA0 = xp[(size_t)s0 * 16]; qA1 = xp[(size_t)s1 * 16];
        qA2 = xp[(size_t)s2 * 16]; qA3 = xp[(size_t)s3 * 16];
        int p = e + 4;
        t0 = col[min(p, last)];     t1 = col[min(p + 1, last)];
        t2 = col[min(p + 2, last)]; t3 = col[min(p + 3, last)];
    }
    for (int b = 0; b < nb; ++b) {
        int4 qB0, qB1, qB2, qB3;
        bool more = (b + 1 < nb);
        if (more) {
            qB0 = xp[(size_t)t0 * 16]; qB1 = xp[(size_t)t1 * 16];
            qB2 = xp[(size_t)t2 * 16]; qB3 = xp[(size_t)t3 * 16];
            int p = e + 8;
            t0 = col[min(p, last)];     t1 = col[min(p + 1, last)];
            t2 = col[min(p + 2, last)]; t3 = col[min(p + 3, last)];
        }
        proc(qA0); proc(qA1); proc(qA2); proc(qA3);
        if (more) { qA0 = qB0; qA1 = qB1; qA2 = qB2; qA3 = qB3; }
        e += 4;
    }
    for (e = r0 + nb * 4; e < r1; ++e)
        proc(xp[(size_t)col[e] * 16]);

    float inv = 1.f / ssum;               // self loop guarantees ssum > 0
    const float* bp = (isv ? biasv : biasm) + s * 8;
    float4 b0 = *(const float4*)bp, b1 = *(const float4*)(bp + 4);
    float r00 = elu1(fmaf(ac0, inv, b0.x));
    float r01 = elu1(fmaf(ac1, inv, b0.y));
    float r02 = elu1(fmaf(ac2, inv, b0.z));
    float r03 = elu1(fmaf(ac3, inv, b0.w));
    float r04 = elu1(fmaf(ac4, inv, b1.x));
    float r05 = elu1(fmaf(ac5, inv, b1.y));
    float r06 = elu1(fmaf(ac6, inv, b1.z));
    float r07 = elu1(fmaf(ac7, inv, b1.w));
    if (HOUT) {
        __half* op = (__half*)(isv ? outv : outm) + (size_t)node * 64 + s * 8;
        h2 p0 = {(_Float16)r00, (_Float16)r01}, p1 = {(_Float16)r02, (_Float16)r03};
        h2 p2 = {(_Float16)r04, (_Float16)r05}, p3 = {(_Float16)r06, (_Float16)r07};
        uint4 pk = {*(unsigned*)&p0, *(unsigned*)&p1, *(unsigned*)&p2, *(unsigned*)&p3};
        *(uint4*)op = pk;
    } else {
        float* op = (float*)(isv ? outv : outm) + (size_t)node * 64 + s * 8;
        float4 r0v = {r00, r01, r02, r03};
        float4 r1v = {r04, r05, r06, r07};
        *(float4*)op = r0v;
        *(float4*)(op + 4) = r1v;
    }

    if (FUSE) {
        // mean lane l gets logvar values from lane l+8 (same 16-lane group)
        float lv0 = __shfl_xor(r00, 8), lv1 = __shfl_xor(r01, 8);
        float lv2 = __shfl_xor(r02, 8), lv3 = __shfl_xor(r03, 8);
        float lv4 = __shfl_xor(r04, 8), lv5 = __shfl_xor(r05, 8);
        float lv6 = __shfl_xor(r06, 8), lv7 = __shfl_xor(r07, 8);
        if (!isv) {
            int g = batch[node];
            const float* ep = eps + (size_t)node * 64 + s * 8;
            float4 e0 = *(const float4*)ep, e1 = *(const float4*)(ep + 4);
            float* zp = zsum + (size_t)g * 64 + s * 8;
            atomicAdd(zp + 0, fmaf(e0.x, __expf(0.5f * lv0), r00));
            atomicAdd(zp + 1, fmaf(e0.y, __expf(0.5f * lv1), r01));
            atomicAdd(zp + 2, fmaf(e0.z, __expf(0.5f * lv2), r02));
            atomicAdd(zp + 3, fmaf(e0.w, __expf(0.5f * lv3), r03));
            atomicAdd(zp + 4, fmaf(e1.x, __expf(0.5f * lv4), r04));
            atomicAdd(zp + 5, fmaf(e1.y, __expf(0.5f * lv5), r05));
            atomicAdd(zp + 6, fmaf(e1.z, __expf(0.5f * lv6), r06));
            atomicAdd(zp + 7, fmaf(e1.w, __expf(0.5f * lv7), r07));
        }
    }
}

// ---- FC head: block per graph (graph size via binary search on sorted batch)

__global__ void k_fchead(const float* __restrict__ zsum, const int* __restrict__ batch,
                         int N,
                         const float* __restrict__ fc1W, const float* __restrict__ fc1b,
                         const float* __restrict__ fc2W, const float* __restrict__ fc2b,
                         float* __restrict__ out) {
    __shared__ float zg[64];
    __shared__ float h1[128];
    __shared__ float lg[2];
    __shared__ int bnd[2];
    int g = blockIdx.x;
    int t = threadIdx.x;
    if (t < 2) {                 // t=0: lower_bound(g), t=1: lower_bound(g+1)
        int tgt = g + t, lo = 0, hi = N;
        while (lo < hi) {
            int m = (lo + hi) >> 1;
            if (batch[m] < tgt) lo = m + 1; else hi = m;
        }
        bnd[t] = lo;
    }
    __syncthreads();
    float cntg = (float)(bnd[1] - bnd[0]);
    if (t < 64) zg[t] = zsum[g * 64 + t] / cntg;
    __syncthreads();
    float h = fc1b[t];
#pragma unroll
    for (int k = 0; k < 64; ++k) h = fmaf(zg[k], fc1W[t * 64 + k], h);
    h1[t] = fmaxf(h, 0.f);
    __syncthreads();
    if (t < 2) {
        float l = fc2b[t];
        for (int k = 0; k < 128; ++k) l = fmaf(h1[k], fc2W[t * 128 + k], l);
        lg[t] = l;
    }
    __syncthreads();
    if (t == 0) {
        float mx = fmaxf(lg[0], lg[1]);
        float lse = mx + logf(expf(lg[0] - mx) + expf(lg[1] - mx));
        out[g * 2 + 0] = lg[0] - lse;
        out[g * 2 + 1] = lg[1] - lse;
    }
}

// ---------------------------------------------------------------------------

extern "C" void kernel_launch(void* const* d_in, const int* in_sizes, int n_in,
                              void* d_out, int out_size, void* d_ws, size_t ws_size,
                              hipStream_t stream) {
    const float* x     = (const float*)d_in[0];
    const float* eps   = (const float*)d_in[1];
    const int*   eidx  = (const int*)d_in[2];
    const int*   batch = (const int*)d_in[3];
    const float* m0_Wl = (const float*)d_in[4];
    const float* m0_bl = (const float*)d_in[5];
    const float* m0_Wr = (const float*)d_in[6];
    const float* m0_br = (const float*)d_in[7];
    const float* m0_att = (const float*)d_in[8];
    const float* m0_bias = (const float*)d_in[9];
    const float* v0_Wl = (const float*)d_in[10];
    const float* v0_bl = (const float*)d_in[11];
    const float* v0_Wr = (const float*)d_in[12];
    const float* v0_br = (const float*)d_in[13];
    const float* v0_att = (const float*)d_in[14];
    const float* v0_bias = (const float*)d_in[15];
    const float* m_Wl = (const float*)d_in[16];
    const float* m_bl = (const float*)d_in[17];
    const float* m_Wr = (const float*)d_in[18];
    const float* m_br = (const float*)d_in[19];
    const float* m_att = (const float*)d_in[20];
    const float* m_bias = (const float*)d_in[21];
    const float* v_Wl = (const float*)d_in[22];
    const float* v_bl = (const float*)d_in[23];
    const float* v_Wr = (const float*)d_in[24];
    const float* v_br = (const float*)d_in[25];
    const float* v_att = (const float*)d_in[26];
    const float* v_bias = (const float*)d_in[27];
    const float* fc1W = (const float*)d_in[28];
    const float* fc1b = (const float*)d_in[29];
    const float* fc2W = (const float*)d_in[30];
    const float* fc2b = (const float*)d_in[31];

    const int N = in_sizes[1] / 64;       // eps is [N,64]
    const int E = in_sizes[2] / 2;        // edge_index is [2,E]
    const int G = (out_size - N * 128) / 2;
    const int nbk = (N + (1 << BSH) - 1) >> BSH;   // buckets (<=1024)
    const int nsb = (N + SNB - 1) / SNB;           // degree-sort blocks
    const int* srcp = eidx;
    const int* dstp = eidx + E;

    char* wsb = (char*)d_ws;
    size_t off = 0;
    auto carve = [&](size_t bytes) -> void* {
        void* p = wsb + off;
        off += (bytes + 255) & ~(size_t)255;
        return p;
    };
    int*    rowptr   = (int*)carve((size_t)(N + 1) * sizeof(int));
    int*    col      = (int*)carve((size_t)E * sizeof(int));
    int*    pairs    = (int*)carve((size_t)E * sizeof(int));
    int*    bcnt     = (int*)carve((size_t)(nbk + 1) * sizeof(int));
    int*    boff     = (int*)carve((size_t)(nbk + 1) * sizeof(int));
    int*    bfill    = (int*)carve((size_t)nbk * sizeof(int));
    int*    nodeof   = (int*)carve((size_t)N * sizeof(int));
    int*    bin_cnt  = (int*)carve(256 * sizeof(int));
    int*    bin_off  = (int*)carve(256 * sizeof(int));
    int*    blk_base = (int*)carve((size_t)nsb * 256 * sizeof(int));
    __half* xlb      = (__half*)carve((size_t)N * 128 * sizeof(__half));
    __half* xrb      = (__half*)carve((size_t)N * 128 * sizeof(__half));
    __half* meanh    = (__half*)carve((size_t)N * 64 * sizeof(__half));
    __half* logvarh  = (__half*)carve((size_t)N * 64 * sizeof(__half));
    float*  zsum     = (float*)carve((size_t)G * 64 * sizeof(float));
    (void)ws_size;

    float* out_logits = (float*)d_out;
    float* mean_buf   = out_logits + (size_t)G * 2;
    float* logvar_buf = mean_buf + (size_t)N * 64;

    const int agrid = (N * 16 + 255) / 256;
    const int tgrid7 = (N * 64 + 255) / 256;
    const int ntiles = (N + 15) / 16;
    const int mgrid = (ntiles + 15) / 16;          // ~4 tiles per wave (W amortized)

    // ---- CSR build (hierarchical binned) ----
    (void)hipMemsetAsync(bcnt, 0, (size_t)nbk * sizeof(int), stream);
    k_hist_bucket<<<256, 256, 0, stream>>>(dstp, E, bcnt, nbk);
    k_scan_buckets<<<1, 1024, 0, stream>>>(bcnt, nbk, boff, bfill, bin_cnt);
    k_binfill<<<(E + CHUNK - 1) / CHUNK, 256, 0, stream>>>(srcp, dstp, E, boff, bfill, pairs);
    k_bucket_csr<<<nbk, 256, 0, stream>>>(pairs, boff, rowptr, col, N, E);

    // ---- degree counting-sort (descending, hierarchical/locality-keeping) ----
    k_deg_hist<<<nsb, 256, 0, stream>>>(rowptr, N, bin_cnt, blk_base);
    k_scan256<<<1, 256, 0, stream>>>(bin_cnt, bin_off, zsum, G);
    k_deg_scatter<<<nsb, 256, 0, stream>>>(rowptr, N, bin_off, blk_base, nodeof);

    // ---- level 0 (input dim 7, both branches fused) ----
    k_transform7<<<tgrid7, 256, 0, stream>>>(x, m0_Wl, m0_bl, m0_Wr, m0_br,
                                             v0_Wl, v0_bl, v0_Wr, v0_br, xlb, xrb, N);
    k_aggregate2<true, false><<<agrid, 256, 0, stream>>>(
        xlb, xrb, m0_att, v0_att, m0_bias, v0_bias,
        rowptr, col, nodeof, meanh, logvarh, N, nullptr, nullptr, nullptr);

    // ---- levels 1..2 (hidden dim 64, fused dual-branch MFMA transforms) ----
    for (int l = 0; l < 2; ++l) {
        k_transform_mfma2<<<dim3(mgrid, 2), 256, 0, stream>>>(
            meanh, logvarh,
            m_Wl + (size_t)l * 4096, m_bl + l * 64, m_Wr + (size_t)l * 4096, m_br + l * 64,
            v_Wl + (size_t)l * 4096, v_bl + l * 64, v_Wr + (size_t)l * 4096, v_br + l * 64,
            xlb, xrb, N);
        if (l == 0)
            k_aggregate2<true, false><<<agrid, 256, 0, stream>>>(
                xlb, xrb, m_att + l * 64, v_att + l * 64, m_bias + l * 64, v_bias + l * 64,
                rowptr, col, nodeof, meanh, logvarh, N, nullptr, nullptr, nullptr);
        else
            k_aggregate2<false, true><<<agrid, 256, 0, stream>>>(
                xlb, xrb, m_att + l * 64, v_att + l * 64, m_bias + l * 64, v_bias + l * 64,
                rowptr, col, nodeof, mean_buf, logvar_buf, N, eps, batch, zsum);
    }

    // ---- FC head (graph counts via binary search on sorted batch) ----
    k_fchead<<<G, 128, 0, stream>>>(zsum, batch, N, fc1W, fc1b, fc2W, fc2b, out_logits);
}

// Round 9
// 406.729 us; speedup vs baseline: 1.6182x; 1.6182x over previous
//
#include <hip/hip_runtime.h>
#include <hip/hip_fp16.h>
#include <math.h>

// ---------------------------------------------------------------------------
// GaussianGAT forward: binned CSR build, hierarchical degree sort (descending
// LPT, locality-preserving within bins), branch-split packed-fp16 GATv2
// aggregation (pipelined gathers, DPP score reduce, fused lrelu/exp2),
// fp16 inter-level buffers, W-amortized MFMA transforms (multi-tile waves),
// separate wave-segment-reduced reparam+pool (NEVER per-element atomics:
// device-scope float atomics cost a 64B coherence-point transaction each —
// R8 lesson: 6.4M scattered atomics = +270us), FC head. 16 dispatches.
// ---------------------------------------------------------------------------

#define BSH 7                 // bucket = dst >> BSH (128 nodes / bucket)
#define BMSK ((1 << BSH) - 1)
#define CHUNK 4096            // edges per binfill block
#define SNB 4096              // nodes per degree-sort block

typedef _Float16 h2 __attribute__((ext_vector_type(2)));
typedef _Float16 h8 __attribute__((ext_vector_type(8)));
typedef float f4 __attribute__((ext_vector_type(4)));

__device__ __forceinline__ float elu1(float v) {
    return v > 0.f ? v : (__expf(v) - 1.f);
}

// 2^x via hardware v_exp_f32 (builtin so the compiler manages trans-op hazards)
__device__ __forceinline__ float exp2fast(float x) {
#if defined(__has_builtin)
#if __has_builtin(__builtin_amdgcn_exp2f)
    return __builtin_amdgcn_exp2f(x);
#else
    return exp2f(x);
#endif
#else
    return exp2f(x);
#endif
}

// f32 += dot(h2, h2) with f32 accumulation (v_dot2_f32_f16)
__device__ __forceinline__ float dot2f(h2 a, h2 b, float c) {
#if defined(__has_builtin)
#if __has_builtin(__builtin_amdgcn_fdot2)
    return __builtin_amdgcn_fdot2(a, b, c, false);
#else
    return fmaf((float)a.x, (float)b.x, fmaf((float)a.y, (float)b.y, c));
#endif
#else
    return fmaf((float)a.x, (float)b.x, fmaf((float)a.y, (float)b.y, c));
#endif
}

// cross-lane permuted copy via DPP (row-aligned 16-lane groups)
template <int CTRL>
__device__ __forceinline__ float dppf(float v) {
    int r = __builtin_amdgcn_update_dpp(0, __builtin_bit_cast(int, v), CTRL, 0xF, 0xF, true);
    return __builtin_bit_cast(float, r);
}

// ---- CSR build -------------------------------------------------------------

__global__ void k_hist_bucket(const int* __restrict__ dst, int E,
                              int* __restrict__ bcnt, int nbk) {
    __shared__ int h[1024];
    for (int i = threadIdx.x; i < 1024; i += blockDim.x) h[i] = 0;
    __syncthreads();
    int stride = gridDim.x * blockDim.x;
    for (int e = blockIdx.x * blockDim.x + threadIdx.x; e < E; e += stride)
        atomicAdd(&h[dst[e] >> BSH], 1);
    __syncthreads();
    for (int i = threadIdx.x; i < nbk; i += blockDim.x)
        if (h[i]) atomicAdd(&bcnt[i], h[i]);
}

// scan buckets; also zero bfill + bin_cnt (saves two memset dispatches)
__global__ void k_scan_buckets(const int* __restrict__ bcnt, int nbk, int* __restrict__ boff,
                               int* __restrict__ bfill, int* __restrict__ bin_cnt) {
    __shared__ int sh[1024];
    int t = threadIdx.x;
    if (t < nbk) bfill[t] = 0;
    if (t < 256) bin_cnt[t] = 0;
    int v = (t < nbk) ? bcnt[t] : 0;
    sh[t] = v;
    __syncthreads();
    for (int o = 1; o < 1024; o <<= 1) {
        int u = (t >= o) ? sh[t - o] : 0;
        __syncthreads();
        sh[t] += u;
        __syncthreads();
    }
    if (t < nbk) boff[t] = sh[t] - v;
    if (t == nbk - 1) boff[nbk] = sh[t];
}

__global__ __launch_bounds__(256) void k_binfill(
    const int* __restrict__ src, const int* __restrict__ dst, int E,
    const int* __restrict__ boff, int* __restrict__ bfill, int* __restrict__ pairs) {
    __shared__ int h[1024];
    __shared__ int sbase[1024];
    int c0 = blockIdx.x * CHUNK;
    int c1 = min(c0 + CHUNK, E);
    for (int i = threadIdx.x; i < 1024; i += 256) h[i] = 0;
    __syncthreads();
    for (int e = c0 + threadIdx.x; e < c1; e += 256)
        atomicAdd(&h[dst[e] >> BSH], 1);
    __syncthreads();
    for (int i = threadIdx.x; i < 1024; i += 256) {
        int c = h[i];
        sbase[i] = c ? (boff[i] + atomicAdd(&bfill[i], c)) : 0;
        h[i] = 0;
    }
    __syncthreads();
    for (int e = c0 + threadIdx.x; e < c1; e += 256) {
        int d = dst[e];
        int b = d >> BSH;
        int off = atomicAdd(&h[b], 1);
        pairs[sbase[b] + off] = (src[e] << BSH) | (d & BMSK);
    }
}

__global__ __launch_bounds__(256) void k_bucket_csr(
    const int* __restrict__ pairs, const int* __restrict__ boff,
    int* __restrict__ rowptr, int* __restrict__ col, int N, int E) {
    __shared__ int deg[128], fill[128], scan[128], base[128];
    int b = blockIdx.x;
    int e0 = boff[b], e1 = boff[b + 1];
    int t = threadIdx.x;
    if (t < 128) { deg[t] = 0; fill[t] = 0; }
    __syncthreads();
    for (int i = e0 + t; i < e1; i += 256)
        atomicAdd(&deg[pairs[i] & BMSK], 1);
    __syncthreads();
    if (t < 128) scan[t] = deg[t];
    __syncthreads();
    for (int o = 1; o < 128; o <<= 1) {
        int u = (t >= o && t < 128) ? scan[t - o] : 0;
        __syncthreads();
        if (t < 128) scan[t] += u;
        __syncthreads();
    }
    if (t < 128) {
        int excl = e0 + scan[t] - deg[t];
        int node = (b << BSH) + t;
        if (node < N) rowptr[node] = excl;
        if (node == N - 1) rowptr[N] = E;
        base[t] = excl;
    }
    __syncthreads();
    for (int i = e0 + t; i < e1; i += 256) {
        int pk = pairs[i];
        int d = pk & BMSK;
        int pos = base[d] + atomicAdd(&fill[d], 1);
        col[pos] = ((unsigned)pk) >> BSH;
    }
}

// ---- degree counting-sort (hierarchical, contention-free, LOCALITY-KEEPING) --
// Key is 255 - min(deg,255): DESCENDING degree (LPT schedule, short tail).
// The blk_base two-pass scheme keeps ascending node-ID runs within each bin.

__global__ __launch_bounds__(256) void k_deg_hist(const int* __restrict__ rowptr, int n,
                                                  int* __restrict__ bin_cnt,
                                                  int* __restrict__ blk_base) {
    __shared__ int h[256];
    h[threadIdx.x] = 0;
    __syncthreads();
    int b0 = blockIdx.x * SNB;
    int b1 = min(b0 + SNB, n);
    for (int i = b0 + threadIdx.x; i < b1; i += 256) {
        int d = 255 - min(rowptr[i + 1] - rowptr[i], 255);
        atomicAdd(&h[d], 1);
    }
    __syncthreads();
    int c = h[threadIdx.x];
    blk_base[blockIdx.x * 256 + threadIdx.x] = c ? atomicAdd(&bin_cnt[threadIdx.x], c) : 0;
}

// scan 256 degree bins; also zero zsum (saves a memset dispatch)
__global__ void k_scan256(const int* __restrict__ bin_cnt, int* __restrict__ bin_off,
                          float* __restrict__ zsum, int G) {
    __shared__ int sh[256];
    int t = threadIdx.x;
    for (int i = t; i < G * 64; i += 256) zsum[i] = 0.f;
    int v = bin_cnt[t];
    sh[t] = v;
    __syncthreads();
    for (int o = 1; o < 256; o <<= 1) {
        int u = (t >= o) ? sh[t - o] : 0;
        __syncthreads();
        sh[t] += u;
        __syncthreads();
    }
    bin_off[t] = sh[t] - v;
}

__global__ __launch_bounds__(256) void k_deg_scatter(const int* __restrict__ rowptr, int n,
                                                     const int* __restrict__ bin_off,
                                                     const int* __restrict__ blk_base,
                                                     int* __restrict__ nodeof) {
    __shared__ int h[256];
    h[threadIdx.x] = 0;
    __syncthreads();
    int b0 = blockIdx.x * SNB;
    int b1 = min(b0 + SNB, n);
    for (int i = b0 + threadIdx.x; i < b1; i += 256) {
        int d = 255 - min(rowptr[i + 1] - rowptr[i], 255);
        int my = atomicAdd(&h[d], 1);
        nodeof[bin_off[d] + blk_base[blockIdx.x * 256 + d] + my] = i;
    }
}

// ---- node transforms -------------------------------------------------------

// level 0, both branches fused: X [n,7] -> xlb/xrb [n,128]
__global__ void k_transform7(const float* __restrict__ X,
                             const float* __restrict__ mWl, const float* __restrict__ mbl,
                             const float* __restrict__ mWr, const float* __restrict__ mbr,
                             const float* __restrict__ vWl, const float* __restrict__ vbl,
                             const float* __restrict__ vWr, const float* __restrict__ vbr,
                             __half* __restrict__ xlb, __half* __restrict__ xrb, int n) {
    int t = blockIdx.x * blockDim.x + threadIdx.x;
    int node = t >> 6;
    if (node >= n) return;
    int h = t & 63;
    float aml = mbl[h], amr = mbr[h], avl = vbl[h], avr = vbr[h];
#pragma unroll
    for (int k = 0; k < 7; ++k) {
        float xv = X[node * 7 + k];
        aml = fmaf(xv, mWl[h * 7 + k], aml);
        amr = fmaf(xv, mWr[h * 7 + k], amr);
        avl = fmaf(xv, vWl[h * 7 + k], avl);
        avr = fmaf(xv, vWr[h * 7 + k], avr);
    }
    size_t o = (size_t)node * 128;
    xlb[o + h] = __float2half(aml);
    xlb[o + 64 + h] = __float2half(avl);
    xrb[o + h] = __float2half(amr);
    xrb[o + 64 + h] = __float2half(avr);
}

// hidden levels via MFMA: out.T = W @ x.T   (M=channel, N=node, K=64)
// blockIdx.y: 0 = mean branch (base 0), 1 = logvar branch (base 64).
// Inputs fp16 [n,64]. Grid sized so each wave sweeps ~4 tiles, amortizing
// the 16KB/wave W-fragment load.
__global__ __launch_bounds__(256) void k_transform_mfma2(
    const __half* __restrict__ Xm, const __half* __restrict__ Xv,
    const float* __restrict__ mWl, const float* __restrict__ mbl,
    const float* __restrict__ mWr, const float* __restrict__ mbr,
    const float* __restrict__ vWl, const float* __restrict__ vbl,
    const float* __restrict__ vWr, const float* __restrict__ vbr,
    __half* __restrict__ xlb, __half* __restrict__ xrb, int n) {
    int brn = blockIdx.y;
    const __half* X = brn ? Xv : Xm;
    const float* Wl = brn ? vWl : mWl;
    const float* bl = brn ? vbl : mbl;
    const float* Wr = brn ? vWr : mWr;
    const float* br = brn ? vbr : mbr;
    int base = brn * 64;

    __shared__ float biasLds[128];
    {
        int t = threadIdx.x;
        if (t < 64) biasLds[t] = bl[t];
        else if (t < 128) biasLds[t] = br[t - 64];
    }
    __syncthreads();
    int lane = threadIdx.x & 63;
    int l16 = lane & 15, lhi = lane >> 4;

    h8 aW[2][8];
    const float* Wp0 = Wl + (size_t)l16 * 64 + lhi * 8;
    const float* Wp1 = Wr + (size_t)l16 * 64 + lhi * 8;
#pragma unroll
    for (int tl = 0; tl < 4; ++tl) {
#pragma unroll
        for (int c = 0; c < 2; ++c) {
            const float* p0 = Wp0 + (size_t)tl * 16 * 64 + c * 32;
            const float* p1 = Wp1 + (size_t)tl * 16 * 64 + c * 32;
            float4 u0 = *(const float4*)p0, u1 = *(const float4*)(p0 + 4);
            float4 v0 = *(const float4*)p1, v1 = *(const float4*)(p1 + 4);
            h8 a0 = {(_Float16)u0.x, (_Float16)u0.y, (_Float16)u0.z, (_Float16)u0.w,
                     (_Float16)u1.x, (_Float16)u1.y, (_Float16)u1.z, (_Float16)u1.w};
            h8 a1 = {(_Float16)v0.x, (_Float16)v0.y, (_Float16)v0.z, (_Float16)v0.w,
                     (_Float16)v1.x, (_Float16)v1.y, (_Float16)v1.z, (_Float16)v1.w};
            aW[0][tl * 2 + c] = a0;
            aW[1][tl * 2 + c] = a1;
        }
    }

    int ntiles = (n + 15) >> 4;
    int wtile = blockIdx.x * 4 + (threadIdx.x >> 6);
    int wstride = gridDim.x * 4;
    for (int tile = wtile; tile < ntiles; tile += wstride) {
        int nb = tile * 16;
        int node = nb + l16;
        int nload = min(node, n - 1);
        h8 Bf[2];
#pragma unroll
        for (int c = 0; c < 2; ++c) {
            const __half* p = X + (size_t)nload * 64 + c * 32 + lhi * 8;
            Bf[c] = *(const h8*)p;
        }
        f4 acc[2][4];
#pragma unroll
        for (int m = 0; m < 2; ++m)
#pragma unroll
            for (int tl = 0; tl < 4; ++tl) {
                f4 a = {0.f, 0.f, 0.f, 0.f};
                a = __builtin_amdgcn_mfma_f32_16x16x32_f16(aW[m][tl * 2 + 0], Bf[0], a, 0, 0, 0);
                a = __builtin_amdgcn_mfma_f32_16x16x32_f16(aW[m][tl * 2 + 1], Bf[1], a, 0, 0, 0);
                acc[m][tl] = a;
            }
        if (node < n) {
#pragma unroll
            for (int m = 0; m < 2; ++m) {
                __half* op = (m ? xrb : xlb) + (size_t)node * 128 + base;
#pragma unroll
                for (int tl = 0; tl < 4; ++tl) {
                    float4 bb = *(const float4*)&biasLds[m * 64 + tl * 16 + 4 * lhi];
                    h2 lo = {(_Float16)(acc[m][tl][0] + bb.x), (_Float16)(acc[m][tl][1] + bb.y)};
                    h2 hi = {(_Float16)(acc[m][tl][2] + bb.z), (_Float16)(acc[m][tl][3] + bb.w)};
                    uint2 pk = {*(unsigned*)&lo, *(unsigned*)&hi};
                    *(uint2*)(op + tl * 16 + 4 * lhi) = pk;
                }
            }
        }
    }
}

// ---- fused dual-branch GATv2 aggregation: branch-split lanes ---------------
// 16 lanes per dst node; lanes 0-7 own mean ch [8s..8s+8), lanes 8-15 logvar.
// HOUT: write fp16 inter-level buffers; else f32 output buffers.

template <bool HOUT>
__global__ __launch_bounds__(256) void k_aggregate2(
    const __half* __restrict__ xlb, const __half* __restrict__ xrb,
    const float* __restrict__ attm, const float* __restrict__ attv,
    const float* __restrict__ biasm, const float* __restrict__ biasv,
    const int* __restrict__ rowptr, const int* __restrict__ col,
    const int* __restrict__ nodeof,
    void* __restrict__ outm, void* __restrict__ outv, int n) {
    int t = blockIdx.x * blockDim.x + threadIdx.x;
    int gid = t >> 4;
    if (gid >= n) return;
    int node = nodeof[gid];
    int l = t & 15;
    int s = l & 7;
    bool isv = l >= 8;

    // my 8 channels of my branch (xlb layout = [mean64|logvar64])
    int4 xri = ((const int4*)(xrb + (size_t)node * 128))[l];
    h2 xr0 = *(h2*)&xri.x, xr1 = *(h2*)&xri.y, xr2 = *(h2*)&xri.z, xr3 = *(h2*)&xri.w;
    const float* ap = (isv ? attv : attm) + s * 8;
    float4 af0 = *(const float4*)ap, af1 = *(const float4*)(ap + 4);
    const float C6 = 0.6f * 1.44269504f;      // fold lrelu + log2(e) for exp2
    const float C4 = 0.4f * 1.44269504f;
    h2 a6_0 = {(_Float16)(af0.x * C6), (_Float16)(af0.y * C6)};
    h2 a6_1 = {(_Float16)(af0.z * C6), (_Float16)(af0.w * C6)};
    h2 a6_2 = {(_Float16)(af1.x * C6), (_Float16)(af1.y * C6)};
    h2 a6_3 = {(_Float16)(af1.z * C6), (_Float16)(af1.w * C6)};
    h2 a4_0 = {(_Float16)(af0.x * C4), (_Float16)(af0.y * C4)};
    h2 a4_1 = {(_Float16)(af0.z * C4), (_Float16)(af0.w * C4)};
    h2 a4_2 = {(_Float16)(af1.x * C4), (_Float16)(af1.y * C4)};
    h2 a4_3 = {(_Float16)(af1.z * C4), (_Float16)(af1.w * C4)};

    float ac0 = 0.f, ac1 = 0.f, ac2 = 0.f, ac3 = 0.f;
    float ac4 = 0.f, ac5 = 0.f, ac6 = 0.f, ac7 = 0.f;
    float ssum = 0.f;

    auto proc = [&](int4 qi) {
        h2 x0 = *(h2*)&qi.x, x1 = *(h2*)&qi.y, x2 = *(h2*)&qi.z, x3 = *(h2*)&qi.w;
        h2 y0 = x0 + xr0, y1 = x1 + xr1, y2 = x2 + xr2, y3 = x3 + xr3;
        int z0i = (*(int*)&y0) & 0x7FFF7FFF;
        int z1i = (*(int*)&y1) & 0x7FFF7FFF;
        int z2i = (*(int*)&y2) & 0x7FFF7FFF;
        int z3i = (*(int*)&y3) & 0x7FFF7FFF;
        h2 z0 = *(h2*)&z0i, z1 = *(h2*)&z1i, z2 = *(h2*)&z2i, z3 = *(h2*)&z3i;
        float sc = dot2f(y0, a6_0, 0.f);
        float sa = dot2f(z0, a4_0, 0.f);
        sc = dot2f(y1, a6_1, sc);
        sa = dot2f(z1, a4_1, sa);
        sc = dot2f(y2, a6_2, sc);
        sa = dot2f(z2, a4_2, sa);
        sc = dot2f(y3, a6_3, sc);
        sa = dot2f(z3, a4_3, sa);
        sc += sa;
        sc += dppf<0xB1>(sc);             // xor 1 (quad_perm 1,0,3,2)
        sc += dppf<0x4E>(sc);             // xor 2 (quad_perm 2,3,0,1)
        sc += dppf<0x141>(sc);            // xor 4 (row_half_mirror)
        float w = exp2fast(sc);           // 2^sc (log2e folded into att)
        ssum += w;
        ac0 = fmaf(w, (float)x0.x, ac0);
        ac1 = fmaf(w, (float)x0.y, ac1);
        ac2 = fmaf(w, (float)x1.x, ac2);
        ac3 = fmaf(w, (float)x1.y, ac3);
        ac4 = fmaf(w, (float)x2.x, ac4);
        ac5 = fmaf(w, (float)x2.y, ac5);
        ac6 = fmaf(w, (float)x3.x, ac6);
        ac7 = fmaf(w, (float)x3.y, ac7);
    };

    int r0 = rowptr[node], r1 = rowptr[node + 1];
    const int4* xp = (const int4*)xlb + l;     // row stride = 16 int4 (256 B)
    int last = r1 - 1;
    int nb = (r1 - r0) >> 2;
    int e = r0;
    int t0 = 0, t1 = 0, t2 = 0, t3 = 0;
    int4 qA0, qA1, qA2, qA3;
    if (nb) {
        int s0 = col[e], s1 = col[e + 1], s2 = col[e + 2], s3 = col[e + 3];
        qA0 = xp[(size_t)s0 * 16]; qA1 = xp[(size_t)s1 * 16];
        qA2 = xp[(size_t)s2 * 16]; qA3 = xp[(size_t)s3 * 16];
        int p = e + 4;
        t0 = col[min(p, last)];     t1 = col[min(p + 1, last)];
        t2 = col[min(p + 2, last)]; t3 = col[min(p + 3, last)];
    }
    for (int b = 0; b < nb; ++b) {
        int4 qB0, qB1, qB2, qB3;
        bool more = (b + 1 < nb);
        if (more) {
            qB0 = xp[(size_t)t0 * 16]; qB1 = xp[(size_t)t1 * 16];
            qB2 = xp[(size_t)t2 * 16]; qB3 = xp[(size_t)t3 * 16];
            int p = e + 8;
            t0 = col[min(p, last)];     t1 = col[min(p + 1, last)];
            t2 = col[min(p + 2, last)]; t3 = col[min(p + 3, last)];
        }
        proc(qA0); proc(qA1); proc(qA2); proc(qA3);
        if (more) { qA0 = qB0; qA1 = qB1; qA2 = qB2; qA3 = qB3; }
        e += 4;
    }
    for (e = r0 + nb * 4; e < r1; ++e)
        proc(xp[(size_t)col[e] * 16]);

    float inv = 1.f / ssum;               // self loop guarantees ssum > 0
    const float* bp = (isv ? biasv : biasm) + s * 8;
    float4 b0 = *(const float4*)bp, b1 = *(const float4*)(bp + 4);
    float r00 = elu1(fmaf(ac0, inv, b0.x));
    float r01 = elu1(fmaf(ac1, inv, b0.y));
    float r02 = elu1(fmaf(ac2, inv, b0.z));
    float r03 = elu1(fmaf(ac3, inv, b0.w));
    float r04 = elu1(fmaf(ac4, inv, b1.x));
    float r05 = elu1(fmaf(ac5, inv, b1.y));
    float r06 = elu1(fmaf(ac6, inv, b1.z));
    float r07 = elu1(fmaf(ac7, inv, b1.w));
    if (HOUT) {
        __half* op = (__half*)(isv ? outv : outm) + (size_t)node * 64 + s * 8;
        h2 p0 = {(_Float16)r00, (_Float16)r01}, p1 = {(_Float16)r02, (_Float16)r03};
        h2 p2 = {(_Float16)r04, (_Float16)r05}, p3 = {(_Float16)r06, (_Float16)r07};
        uint4 pk = {*(unsigned*)&p0, *(unsigned*)&p1, *(unsigned*)&p2, *(unsigned*)&p3};
        *(uint4*)op = pk;
    } else {
        float* op = (float*)(isv ? outv : outm) + (size_t)node * 64 + s * 8;
        float4 r0v = {r00, r01, r02, r03};
        float4 r1v = {r04, r05, r06, r07};
        *(float4*)op = r0v;
        *(float4*)(op + 4) = r1v;
    }
}

// ---- reparameterize + segment-mean-pool (batch is sorted) ------------------
// One wave per 16 nodes; per-wave segment accumulation => ~1-2 atomics per
// (graph,lane) instead of per-node scattering (R8 lesson).

__global__ void k_zpool(const float* __restrict__ mean, const float* __restrict__ logvar,
                        const float* __restrict__ eps, const int* __restrict__ batch,
                        float* __restrict__ zsum, int n) {
    int wave = blockIdx.x * 4 + (threadIdx.x >> 6);
    int lane = threadIdx.x & 63;
    int n0 = wave * 16;
    if (n0 >= n) return;
    int n1 = min(n0 + 16, n);
    float acc = 0.f;
    int gcur = -1;
    for (int nd = n0; nd < n1; ++nd) {
        int g = batch[nd];
        if (g != gcur) {
            if (gcur >= 0) atomicAdd(&zsum[gcur * 64 + lane], acc);
            gcur = g; acc = 0.f;
        }
        size_t o = (size_t)nd * 64 + lane;
        acc += fmaf(eps[o], __expf(0.5f * logvar[o]), mean[o]);
    }
    if (gcur >= 0) atomicAdd(&zsum[gcur * 64 + lane], acc);
}

// ---- FC head: block per graph (graph size via binary search on sorted batch)

__global__ void k_fchead(const float* __restrict__ zsum, const int* __restrict__ batch,
                         int N,
                         const float* __restrict__ fc1W, const float* __restrict__ fc1b,
                         const float* __restrict__ fc2W, const float* __restrict__ fc2b,
                         float* __restrict__ out) {
    __shared__ float zg[64];
    __shared__ float h1[128];
    __shared__ float lg[2];
    __shared__ int bnd[2];
    int g = blockIdx.x;
    int t = threadIdx.x;
    if (t < 2) {                 // t=0: lower_bound(g), t=1: lower_bound(g+1)
        int tgt = g + t, lo = 0, hi = N;
        while (lo < hi) {
            int m = (lo + hi) >> 1;
            if (batch[m] < tgt) lo = m + 1; else hi = m;
        }
        bnd[t] = lo;
    }
    __syncthreads();
    float cntg = (float)(bnd[1] - bnd[0]);
    if (t < 64) zg[t] = zsum[g * 64 + t] / cntg;
    __syncthreads();
    float h = fc1b[t];
#pragma unroll
    for (int k = 0; k < 64; ++k) h = fmaf(zg[k], fc1W[t * 64 + k], h);
    h1[t] = fmaxf(h, 0.f);
    __syncthreads();
    if (t < 2) {
        float l = fc2b[t];
        for (int k = 0; k < 128; ++k) l = fmaf(h1[k], fc2W[t * 128 + k], l);
        lg[t] = l;
    }
    __syncthreads();
    if (t == 0) {
        float mx = fmaxf(lg[0], lg[1]);
        float lse = mx + logf(expf(lg[0] - mx) + expf(lg[1] - mx));
        out[g * 2 + 0] = lg[0] - lse;
        out[g * 2 + 1] = lg[1] - lse;
    }
}

// ---------------------------------------------------------------------------

extern "C" void kernel_launch(void* const* d_in, const int* in_sizes, int n_in,
                              void* d_out, int out_size, void* d_ws, size_t ws_size,
                              hipStream_t stream) {
    const float* x     = (const float*)d_in[0];
    const float* eps   = (const float*)d_in[1];
    const int*   eidx  = (const int*)d_in[2];
    const int*   batch = (const int*)d_in[3];
    const float* m0_Wl = (const float*)d_in[4];
    const float* m0_bl = (const float*)d_in[5];
    const float* m0_Wr = (const float*)d_in[6];
    const float* m0_br = (const float*)d_in[7];
    const float* m0_att = (const float*)d_in[8];
    const float* m0_bias = (const float*)d_in[9];
    const float* v0_Wl = (const float*)d_in[10];
    const float* v0_bl = (const float*)d_in[11];
    const float* v0_Wr = (const float*)d_in[12];
    const float* v0_br = (const float*)d_in[13];
    const float* v0_att = (const float*)d_in[14];
    const float* v0_bias = (const float*)d_in[15];
    const float* m_Wl = (const float*)d_in[16];
    const float* m_bl = (const float*)d_in[17];
    const float* m_Wr = (const float*)d_in[18];
    const float* m_br = (const float*)d_in[19];
    const float* m_att = (const float*)d_in[20];
    const float* m_bias = (const float*)d_in[21];
    const float* v_Wl = (const float*)d_in[22];
    const float* v_bl = (const float*)d_in[23];
    const float* v_Wr = (const float*)d_in[24];
    const float* v_br = (const float*)d_in[25];
    const float* v_att = (const float*)d_in[26];
    const float* v_bias = (const float*)d_in[27];
    const float* fc1W = (const float*)d_in[28];
    const float* fc1b = (const float*)d_in[29];
    const float* fc2W = (const float*)d_in[30];
    const float* fc2b = (const float*)d_in[31];

    const int N = in_sizes[1] / 64;       // eps is [N,64]
    const int E = in_sizes[2] / 2;        // edge_index is [2,E]
    const int G = (out_size - N * 128) / 2;
    const int nbk = (N + (1 << BSH) - 1) >> BSH;   // buckets (<=1024)
    const int nsb = (N + SNB - 1) / SNB;           // degree-sort blocks
    const int* srcp = eidx;
    const int* dstp = eidx + E;

    char* wsb = (char*)d_ws;
    size_t off = 0;
    auto carve = [&](size_t bytes) -> void* {
        void* p = wsb + off;
        off += (bytes + 255) & ~(size_t)255;
        return p;
    };
    int*    rowptr   = (int*)carve((size_t)(N + 1) * sizeof(int));
    int*    col      = (int*)carve((size_t)E * sizeof(int));
    int*    pairs    = (int*)carve((size_t)E * sizeof(int));
    int*    bcnt     = (int*)carve((size_t)(nbk + 1) * sizeof(int));
    int*    boff     = (int*)carve((size_t)(nbk + 1) * sizeof(int));
    int*    bfill    = (int*)carve((size_t)nbk * sizeof(int));
    int*    nodeof   = (int*)carve((size_t)N * sizeof(int));
    int*    bin_cnt  = (int*)carve(256 * sizeof(int));
    int*    bin_off  = (int*)carve(256 * sizeof(int));
    int*    blk_base = (int*)carve((size_t)nsb * 256 * sizeof(int));
    __half* xlb      = (__half*)carve((size_t)N * 128 * sizeof(__half));
    __half* xrb      = (__half*)carve((size_t)N * 128 * sizeof(__half));
    __half* meanh    = (__half*)carve((size_t)N * 64 * sizeof(__half));
    __half* logvarh  = (__half*)carve((size_t)N * 64 * sizeof(__half));
    float*  zsum     = (float*)carve((size_t)G * 64 * sizeof(float));
    (void)ws_size;

    float* out_logits = (float*)d_out;
    float* mean_buf   = out_logits + (size_t)G * 2;
    float* logvar_buf = mean_buf + (size_t)N * 64;

    const int agrid = (N * 16 + 255) / 256;
    const int tgrid7 = (N * 64 + 255) / 256;
    const int ntiles = (N + 15) / 16;
    const int mgrid = (ntiles + 15) / 16;          // ~4 tiles per wave (W amortized)
    const int zgrid = ((N + 15) / 16 + 3) / 4;     // one wave per 16 nodes

    // ---- CSR build (hierarchical binned) ----
    (void)hipMemsetAsync(bcnt, 0, (size_t)nbk * sizeof(int), stream);
    k_hist_bucket<<<256, 256, 0, stream>>>(dstp, E, bcnt, nbk);
    k_scan_buckets<<<1, 1024, 0, stream>>>(bcnt, nbk, boff, bfill, bin_cnt);
    k_binfill<<<(E + CHUNK - 1) / CHUNK, 256, 0, stream>>>(srcp, dstp, E, boff, bfill, pairs);
    k_bucket_csr<<<nbk, 256, 0, stream>>>(pairs, boff, rowptr, col, N, E);

    // ---- degree counting-sort (descending, hierarchical/locality-keeping) ----
    k_deg_hist<<<nsb, 256, 0, stream>>>(rowptr, N, bin_cnt, blk_base);
    k_scan256<<<1, 256, 0, stream>>>(bin_cnt, bin_off, zsum, G);
    k_deg_scatter<<<nsb, 256, 0, stream>>>(rowptr, N, bin_off, blk_base, nodeof);

    // ---- level 0 (input dim 7, both branches fused) ----
    k_transform7<<<tgrid7, 256, 0, stream>>>(x, m0_Wl, m0_bl, m0_Wr, m0_br,
                                             v0_Wl, v0_bl, v0_Wr, v0_br, xlb, xrb, N);
    k_aggregate2<true><<<agrid, 256, 0, stream>>>(
        xlb, xrb, m0_att, v0_att, m0_bias, v0_bias,
        rowptr, col, nodeof, meanh, logvarh, N);

    // ---- levels 1..2 (hidden dim 64, fused dual-branch MFMA transforms) ----
    for (int l = 0; l < 2; ++l) {
        k_transform_mfma2<<<dim3(mgrid, 2), 256, 0, stream>>>(
            meanh, logvarh,
            m_Wl + (size_t)l * 4096, m_bl + l * 64, m_Wr + (size_t)l * 4096, m_br + l * 64,
            v_Wl + (size_t)l * 4096, v_bl + l * 64, v_Wr + (size_t)l * 4096, v_br + l * 64,
            xlb, xrb, N);
        if (l == 0)
            k_aggregate2<true><<<agrid, 256, 0, stream>>>(
                xlb, xrb, m_att + l * 64, v_att + l * 64, m_bias + l * 64, v_bias + l * 64,
                rowptr, col, nodeof, meanh, logvarh, N);
        else
            k_aggregate2<false><<<agrid, 256, 0, stream>>>(
                xlb, xrb, m_att + l * 64, v_att + l * 64, m_bias + l * 64, v_bias + l * 64,
                rowptr, col, nodeof, mean_buf, logvar_buf, N);
    }

    // ---- reparameterize + pool + FC head ----
    k_zpool<<<zgrid, 256, 0, stream>>>(mean_buf, logvar_buf, eps, batch, zsum, N);
    k_fchead<<<G, 128, 0, stream>>>(zsum, batch, N, fc1W, fc1b, fc2W, fc2b, out_logits);
}

// Round 10
// 396.453 us; speedup vs baseline: 1.6602x; 1.0259x over previous
//
#include <hip/hip_runtime.h>
#include <hip/hip_fp16.h>
#include <math.h>

// ---------------------------------------------------------------------------
// GaussianGAT forward: binned CSR build, hierarchical degree sort (descending
// LPT, locality-preserving within bins — SNB=4096 granularity is REQUIRED:
// per-(block,bin) ascending runs of ~80 node IDs are what coalesce the
// aggregate; finer tickets re-randomize (R5)), branch-split packed-fp16
// GATv2 aggregation (pipelined gathers, DPP score reduce, fused lrelu/exp2),
// fp16 inter-level buffers, W-amortized + Bf-pipelined MFMA transforms,
// packed transform7 (+ folded degree-scatter), wave-segment-reduced
// reparam+pool (NEVER per-element device-scope atomics: 64B coherence-point
// granule, R8), FC head. 15 dispatches.
// ---------------------------------------------------------------------------

#define BSH 7                 // bucket = dst >> BSH (128 nodes / bucket)
#define BMSK ((1 << BSH) - 1)
#define CHUNK 4096            // edges per binfill block
#define SNB 4096              // nodes per degree-sort block (locality knob!)

typedef _Float16 h2 __attribute__((ext_vector_type(2)));
typedef _Float16 h8 __attribute__((ext_vector_type(8)));
typedef float f4 __attribute__((ext_vector_type(4)));

__device__ __forceinline__ float elu1(float v) {
    return v > 0.f ? v : (__expf(v) - 1.f);
}

// 2^x via hardware v_exp_f32 (builtin so the compiler manages trans-op hazards)
__device__ __forceinline__ float exp2fast(float x) {
#if defined(__has_builtin)
#if __has_builtin(__builtin_amdgcn_exp2f)
    return __builtin_amdgcn_exp2f(x);
#else
    return exp2f(x);
#endif
#else
    return exp2f(x);
#endif
}

// f32 += dot(h2, h2) with f32 accumulation (v_dot2_f32_f16)
__device__ __forceinline__ float dot2f(h2 a, h2 b, float c) {
#if defined(__has_builtin)
#if __has_builtin(__builtin_amdgcn_fdot2)
    return __builtin_amdgcn_fdot2(a, b, c, false);
#else
    return fmaf((float)a.x, (float)b.x, fmaf((float)a.y, (float)b.y, c));
#endif
#else
    return fmaf((float)a.x, (float)b.x, fmaf((float)a.y, (float)b.y, c));
#endif
}

// cross-lane permuted copy via DPP (row-aligned 16-lane groups)
template <int CTRL>
__device__ __forceinline__ float dppf(float v) {
    int r = __builtin_amdgcn_update_dpp(0, __builtin_bit_cast(int, v), CTRL, 0xF, 0xF, true);
    return __builtin_bit_cast(float, r);
}

// ---- CSR build -------------------------------------------------------------

__global__ void k_hist_bucket(const int* __restrict__ dst, int E,
                              int* __restrict__ bcnt, int nbk) {
    __shared__ int h[1024];
    for (int i = threadIdx.x; i < 1024; i += blockDim.x) h[i] = 0;
    __syncthreads();
    int stride = gridDim.x * blockDim.x;
    for (int e = blockIdx.x * blockDim.x + threadIdx.x; e < E; e += stride)
        atomicAdd(&h[dst[e] >> BSH], 1);
    __syncthreads();
    for (int i = threadIdx.x; i < nbk; i += blockDim.x)
        if (h[i]) atomicAdd(&bcnt[i], h[i]);
}

// scan buckets; also zero bfill + bin_cnt (saves two memset dispatches)
__global__ void k_scan_buckets(const int* __restrict__ bcnt, int nbk, int* __restrict__ boff,
                               int* __restrict__ bfill, int* __restrict__ bin_cnt) {
    __shared__ int sh[1024];
    int t = threadIdx.x;
    if (t < nbk) bfill[t] = 0;
    if (t < 256) bin_cnt[t] = 0;
    int v = (t < nbk) ? bcnt[t] : 0;
    sh[t] = v;
    __syncthreads();
    for (int o = 1; o < 1024; o <<= 1) {
        int u = (t >= o) ? sh[t - o] : 0;
        __syncthreads();
        sh[t] += u;
        __syncthreads();
    }
    if (t < nbk) boff[t] = sh[t] - v;
    if (t == nbk - 1) boff[nbk] = sh[t];
}

__global__ __launch_bounds__(256) void k_binfill(
    const int* __restrict__ src, const int* __restrict__ dst, int E,
    const int* __restrict__ boff, int* __restrict__ bfill, int* __restrict__ pairs) {
    __shared__ int h[1024];
    __shared__ int sbase[1024];
    int c0 = blockIdx.x * CHUNK;
    int c1 = min(c0 + CHUNK, E);
    for (int i = threadIdx.x; i < 1024; i += 256) h[i] = 0;
    __syncthreads();
    for (int e = c0 + threadIdx.x; e < c1; e += 256)
        atomicAdd(&h[dst[e] >> BSH], 1);
    __syncthreads();
    for (int i = threadIdx.x; i < 1024; i += 256) {
        int c = h[i];
        sbase[i] = c ? (boff[i] + atomicAdd(&bfill[i], c)) : 0;
        h[i] = 0;
    }
    __syncthreads();
    for (int e = c0 + threadIdx.x; e < c1; e += 256) {
        int d = dst[e];
        int b = d >> BSH;
        int off = atomicAdd(&h[b], 1);
        pairs[sbase[b] + off] = (src[e] << BSH) | (d & BMSK);
    }
}

__global__ __launch_bounds__(256) void k_bucket_csr(
    const int* __restrict__ pairs, const int* __restrict__ boff,
    int* __restrict__ rowptr, int* __restrict__ col, int N, int E) {
    __shared__ int deg[128], fill[128], scan[128], base[128];
    int b = blockIdx.x;
    int e0 = boff[b], e1 = boff[b + 1];
    int t = threadIdx.x;
    if (t < 128) { deg[t] = 0; fill[t] = 0; }
    __syncthreads();
    for (int i = e0 + t; i < e1; i += 256)
        atomicAdd(&deg[pairs[i] & BMSK], 1);
    __syncthreads();
    if (t < 128) scan[t] = deg[t];
    __syncthreads();
    for (int o = 1; o < 128; o <<= 1) {
        int u = (t >= o && t < 128) ? scan[t - o] : 0;
        __syncthreads();
        if (t < 128) scan[t] += u;
        __syncthreads();
    }
    if (t < 128) {
        int excl = e0 + scan[t] - deg[t];
        int node = (b << BSH) + t;
        if (node < N) rowptr[node] = excl;
        if (node == N - 1) rowptr[N] = E;
        base[t] = excl;
    }
    __syncthreads();
    for (int i = e0 + t; i < e1; i += 256) {
        int pk = pairs[i];
        int d = pk & BMSK;
        int pos = base[d] + atomicAdd(&fill[d], 1);
        col[pos] = ((unsigned)pk) >> BSH;
    }
}

// ---- degree counting-sort (hierarchical, SNB=4096 granularity) -------------
// Key is 255 - min(deg,255): DESCENDING degree (LPT schedule, short tail).

__global__ __launch_bounds__(256) void k_deg_hist(const int* __restrict__ rowptr, int n,
                                                  int* __restrict__ bin_cnt,
                                                  int* __restrict__ blk_base) {
    __shared__ int h[256];
    h[threadIdx.x] = 0;
    __syncthreads();
    int b0 = blockIdx.x * SNB;
    int b1 = min(b0 + SNB, n);
    for (int i = b0 + threadIdx.x; i < b1; i += 256) {
        int d = 255 - min(rowptr[i + 1] - rowptr[i], 255);
        atomicAdd(&h[d], 1);
    }
    __syncthreads();
    int c = h[threadIdx.x];
    blk_base[blockIdx.x * 256 + threadIdx.x] = c ? atomicAdd(&bin_cnt[threadIdx.x], c) : 0;
}

// scan 256 degree bins; also zero zsum (saves a memset dispatch)
__global__ void k_scan256(const int* __restrict__ bin_cnt, int* __restrict__ bin_off,
                          float* __restrict__ zsum, int G) {
    __shared__ int sh[256];
    int t = threadIdx.x;
    for (int i = t; i < G * 64; i += 256) zsum[i] = 0.f;
    int v = bin_cnt[t];
    sh[t] = v;
    __syncthreads();
    for (int o = 1; o < 256; o <<= 1) {
        int u = (t >= o) ? sh[t - o] : 0;
        __syncthreads();
        sh[t] += u;
        __syncthreads();
    }
    bin_off[t] = sh[t] - v;
}

// ---- node transforms -------------------------------------------------------

// level 0, both branches fused: X [n,7] -> xlb/xrb [n,128].
// 32 threads/node, 2 channels/thread, h2 (4B/lane) packed stores.
// Blocks < nsb ALSO run the degree-scatter body (identical SNB-granularity
// logic, folded here to save a dispatch; runs after k_scan256).
__global__ __launch_bounds__(256) void k_transform7(
    const float* __restrict__ X,
    const float* __restrict__ mWl, const float* __restrict__ mbl,
    const float* __restrict__ mWr, const float* __restrict__ mbr,
    const float* __restrict__ vWl, const float* __restrict__ vbl,
    const float* __restrict__ vWr, const float* __restrict__ vbr,
    __half* __restrict__ xlb, __half* __restrict__ xrb, int n,
    const int* __restrict__ rowptr, const int* __restrict__ bin_off,
    const int* __restrict__ blk_base, int* __restrict__ nodeof, int nsb) {
    if (blockIdx.x < (unsigned)nsb) {      // folded k_deg_scatter
        __shared__ int h[256];
        h[threadIdx.x] = 0;
        __syncthreads();
        int b0 = blockIdx.x * SNB;
        int b1 = min(b0 + SNB, n);
        for (int i = b0 + threadIdx.x; i < b1; i += 256) {
            int d = 255 - min(rowptr[i + 1] - rowptr[i], 255);
            int my = atomicAdd(&h[d], 1);
            nodeof[bin_off[d] + blk_base[blockIdx.x * 256 + d] + my] = i;
        }
    }
    int t = blockIdx.x * blockDim.x + threadIdx.x;
    int node = t >> 5;
    if (node >= n) return;
    int c2 = (t & 31) * 2;                 // channel pair
    float aml0 = mbl[c2], aml1 = mbl[c2 + 1];
    float amr0 = mbr[c2], amr1 = mbr[c2 + 1];
    float avl0 = vbl[c2], avl1 = vbl[c2 + 1];
    float avr0 = vbr[c2], avr1 = vbr[c2 + 1];
#pragma unroll
    for (int k = 0; k < 7; ++k) {
        float xv = X[node * 7 + k];
        aml0 = fmaf(xv, mWl[c2 * 7 + k], aml0);
        aml1 = fmaf(xv, mWl[(c2 + 1) * 7 + k], aml1);
        amr0 = fmaf(xv, mWr[c2 * 7 + k], amr0);
        amr1 = fmaf(xv, mWr[(c2 + 1) * 7 + k], amr1);
        avl0 = fmaf(xv, vWl[c2 * 7 + k], avl0);
        avl1 = fmaf(xv, vWl[(c2 + 1) * 7 + k], avl1);
        avr0 = fmaf(xv, vWr[c2 * 7 + k], avr0);
        avr1 = fmaf(xv, vWr[(c2 + 1) * 7 + k], avr1);
    }
    size_t o = (size_t)node * 128;
    h2 pml = {(_Float16)aml0, (_Float16)aml1};
    h2 pvl = {(_Float16)avl0, (_Float16)avl1};
    h2 pmr = {(_Float16)amr0, (_Float16)amr1};
    h2 pvr = {(_Float16)avr0, (_Float16)avr1};
    *(h2*)(xlb + o + c2) = pml;
    *(h2*)(xlb + o + 64 + c2) = pvl;
    *(h2*)(xrb + o + c2) = pmr;
    *(h2*)(xrb + o + 64 + c2) = pvr;
}

// hidden levels via MFMA: out.T = W @ x.T   (M=channel, N=node, K=64)
// blockIdx.y: 0 = mean branch (base 0), 1 = logvar branch (base 64).
// Inputs fp16 [n,64]. Each wave sweeps ~4 tiles (W amortized); Bf loads for
// tile t+1 are issued BEFORE tile t's MFMAs (software pipeline hides the
// ~500cy global latency that otherwise serializes each tile).
__global__ __launch_bounds__(256) void k_transform_mfma2(
    const __half* __restrict__ Xm, const __half* __restrict__ Xv,
    const float* __restrict__ mWl, const float* __restrict__ mbl,
    const float* __restrict__ mWr, const float* __restrict__ mbr,
    const float* __restrict__ vWl, const float* __restrict__ vbl,
    const float* __restrict__ vWr, const float* __restrict__ vbr,
    __half* __restrict__ xlb, __half* __restrict__ xrb, int n) {
    int brn = blockIdx.y;
    const __half* X = brn ? Xv : Xm;
    const float* Wl = brn ? vWl : mWl;
    const float* bl = brn ? vbl : mbl;
    const float* Wr = brn ? vWr : mWr;
    const float* br = brn ? vbr : mbr;
    int base = brn * 64;

    __shared__ float biasLds[128];
    {
        int t = threadIdx.x;
        if (t < 64) biasLds[t] = bl[t];
        else if (t < 128) biasLds[t] = br[t - 64];
    }
    __syncthreads();
    int lane = threadIdx.x & 63;
    int l16 = lane & 15, lhi = lane >> 4;

    h8 aW[2][8];
    const float* Wp0 = Wl + (size_t)l16 * 64 + lhi * 8;
    const float* Wp1 = Wr + (size_t)l16 * 64 + lhi * 8;
#pragma unroll
    for (int tl = 0; tl < 4; ++tl) {
#pragma unroll
        for (int c = 0; c < 2; ++c) {
            const float* p0 = Wp0 + (size_t)tl * 16 * 64 + c * 32;
            const float* p1 = Wp1 + (size_t)tl * 16 * 64 + c * 32;
            float4 u0 = *(const float4*)p0, u1 = *(const float4*)(p0 + 4);
            float4 v0 = *(const float4*)p1, v1 = *(const float4*)(p1 + 4);
            h8 a0 = {(_Float16)u0.x, (_Float16)u0.y, (_Float16)u0.z, (_Float16)u0.w,
                     (_Float16)u1.x, (_Float16)u1.y, (_Float16)u1.z, (_Float16)u1.w};
            h8 a1 = {(_Float16)v0.x, (_Float16)v0.y, (_Float16)v0.z, (_Float16)v0.w,
                     (_Float16)v1.x, (_Float16)v1.y, (_Float16)v1.z, (_Float16)v1.w};
            aW[0][tl * 2 + c] = a0;
            aW[1][tl * 2 + c] = a1;
        }
    }

    int ntiles = (n + 15) >> 4;
    int wstride = gridDim.x * 4;
    int tile = blockIdx.x * 4 + (threadIdx.x >> 6);
    h8 Bf[2];
    if (tile < ntiles) {
        int nload = min(tile * 16 + l16, n - 1);
        const __half* p = X + (size_t)nload * 64 + lhi * 8;
        Bf[0] = *(const h8*)p;
        Bf[1] = *(const h8*)(p + 32);
    }
    for (; tile < ntiles; tile += wstride) {
        int next = tile + wstride;
        h8 BfN[2];
        if (next < ntiles) {               // prefetch next tile's fragments
            int nloadN = min(next * 16 + l16, n - 1);
            const __half* p = X + (size_t)nloadN * 64 + lhi * 8;
            BfN[0] = *(const h8*)p;
            BfN[1] = *(const h8*)(p + 32);
        }
        f4 acc[2][4];
#pragma unroll
        for (int m = 0; m < 2; ++m)
#pragma unroll
            for (int tl = 0; tl < 4; ++tl) {
                f4 a = {0.f, 0.f, 0.f, 0.f};
                a = __builtin_amdgcn_mfma_f32_16x16x32_f16(aW[m][tl * 2 + 0], Bf[0], a, 0, 0, 0);
                a = __builtin_amdgcn_mfma_f32_16x16x32_f16(aW[m][tl * 2 + 1], Bf[1], a, 0, 0, 0);
                acc[m][tl] = a;
            }
        int node = tile * 16 + l16;
        if (node < n) {
#pragma unroll
            for (int m = 0; m < 2; ++m) {
                __half* op = (m ? xrb : xlb) + (size_t)node * 128 + base;
#pragma unroll
                for (int tl = 0; tl < 4; ++tl) {
                    float4 bb = *(const float4*)&biasLds[m * 64 + tl * 16 + 4 * lhi];
                    h2 lo = {(_Float16)(acc[m][tl][0] + bb.x), (_Float16)(acc[m][tl][1] + bb.y)};
                    h2 hi = {(_Float16)(acc[m][tl][2] + bb.z), (_Float16)(acc[m][tl][3] + bb.w)};
                    uint2 pk = {*(unsigned*)&lo, *(unsigned*)&hi};
                    *(uint2*)(op + tl * 16 + 4 * lhi) = pk;
                }
            }
        }
        if (next < ntiles) { Bf[0] = BfN[0]; Bf[1] = BfN[1]; }
    }
}

// ---- fused dual-branch GATv2 aggregation: branch-split lanes ---------------
// 16 lanes per dst node; lanes 0-7 own mean ch [8s..8s+8), lanes 8-15 logvar.
// HOUT: write fp16 inter-level buffers; else f32 output buffers.

template <bool HOUT>
__global__ __launch_bounds__(256) void k_aggregate2(
    const __half* __restrict__ xlb, const __half* __restrict__ xrb,
    const float* __restrict__ attm, const float* __restrict__ attv,
    const float* __restrict__ biasm, const float* __restrict__ biasv,
    const int* __restrict__ rowptr, const int* __restrict__ col,
    const int* __restrict__ nodeof,
    void* __restrict__ outm, void* __restrict__ outv, int n) {
    int t = blockIdx.x * blockDim.x + threadIdx.x;
    int gid = t >> 4;
    if (gid >= n) return;
    int node = nodeof[gid];
    int l = t & 15;
    int s = l & 7;
    bool isv = l >= 8;

    // my 8 channels of my branch (xlb layout = [mean64|logvar64])
    int4 xri = ((const int4*)(xrb + (size_t)node * 128))[l];
    h2 xr0 = *(h2*)&xri.x, xr1 = *(h2*)&xri.y, xr2 = *(h2*)&xri.z, xr3 = *(h2*)&xri.w;
    const float* ap = (isv ? attv : attm) + s * 8;
    float4 af0 = *(const float4*)ap, af1 = *(const float4*)(ap + 4);
    const float C6 = 0.6f * 1.44269504f;      // fold lrelu + log2(e) for exp2
    const float C4 = 0.4f * 1.44269504f;
    h2 a6_0 = {(_Float16)(af0.x * C6), (_Float16)(af0.y * C6)};
    h2 a6_1 = {(_Float16)(af0.z * C6), (_Float16)(af0.w * C6)};
    h2 a6_2 = {(_Float16)(af1.x * C6), (_Float16)(af1.y * C6)};
    h2 a6_3 = {(_Float16)(af1.z * C6), (_Float16)(af1.w * C6)};
    h2 a4_0 = {(_Float16)(af0.x * C4), (_Float16)(af0.y * C4)};
    h2 a4_1 = {(_Float16)(af0.z * C4), (_Float16)(af0.w * C4)};
    h2 a4_2 = {(_Float16)(af1.x * C4), (_Float16)(af1.y * C4)};
    h2 a4_3 = {(_Float16)(af1.z * C4), (_Float16)(af1.w * C4)};

    float ac0 = 0.f, ac1 = 0.f, ac2 = 0.f, ac3 = 0.f;
    float ac4 = 0.f, ac5 = 0.f, ac6 = 0.f, ac7 = 0.f;
    float ssum = 0.f;

    auto proc = [&](int4 qi) {
        h2 x0 = *(h2*)&qi.x, x1 = *(h2*)&qi.y, x2 = *(h2*)&qi.z, x3 = *(h2*)&qi.w;
        h2 y0 = x0 + xr0, y1 = x1 + xr1, y2 = x2 + xr2, y3 = x3 + xr3;
        int z0i = (*(int*)&y0) & 0x7FFF7FFF;
        int z1i = (*(int*)&y1) & 0x7FFF7FFF;
        int z2i = (*(int*)&y2) & 0x7FFF7FFF;
        int z3i = (*(int*)&y3) & 0x7FFF7FFF;
        h2 z0 = *(h2*)&z0i, z1 = *(h2*)&z1i, z2 = *(h2*)&z2i, z3 = *(h2*)&z3i;
        float sc = dot2f(y0, a6_0, 0.f);
        float sa = dot2f(z0, a4_0, 0.f);
        sc = dot2f(y1, a6_1, sc);
        sa = dot2f(z1, a4_1, sa);
        sc = dot2f(y2, a6_2, sc);
        sa = dot2f(z2, a4_2, sa);
        sc = dot2f(y3, a6_3, sc);
        sa = dot2f(z3, a4_3, sa);
        sc += sa;
        sc += dppf<0xB1>(sc);             // xor 1 (quad_perm 1,0,3,2)
        sc += dppf<0x4E>(sc);             // xor 2 (quad_perm 2,3,0,1)
        sc += dppf<0x141>(sc);            // xor 4 (row_half_mirror)
        float w = exp2fast(sc);           // 2^sc (log2e folded into att)
        ssum += w;
        ac0 = fmaf(w, (float)x0.x, ac0);
        ac1 = fmaf(w, (float)x0.y, ac1);
        ac2 = fmaf(w, (float)x1.x, ac2);
        ac3 = fmaf(w, (float)x1.y, ac3);
        ac4 = fmaf(w, (float)x2.x, ac4);
        ac5 = fmaf(w, (float)x2.y, ac5);
        ac6 = fmaf(w, (float)x3.x, ac6);
        ac7 = fmaf(w, (float)x3.y, ac7);
    };

    int r0 = rowptr[node], r1 = rowptr[node + 1];
    const int4* xp = (const int4*)xlb + l;     // row stride = 16 int4 (256 B)
    int last = r1 - 1;
    int nb = (r1 - r0) >> 2;
    int e = r0;
    int t0 = 0, t1 = 0, t2 = 0, t3 = 0;
    int4 qA0, qA1, qA2, qA3;
    if (nb) {
        int s0 = col[e], s1 = col[e + 1], s2 = col[e + 2], s3 = col[e + 3];
        qA0 = xp[(size_t)s0 * 16]; qA1 = xp[(size_t)s1 * 16];
        qA2 = xp[(size_t)s2 * 16]; qA3 = xp[(size_t)s3 * 16];
        int p = e + 4;
        t0 = col[min(p, last)];     t1 = col[min(p + 1, last)];
        t2 = col[min(p + 2, last)]; t3 = col[min(p + 3, last)];
    }
    for (int b = 0; b < nb; ++b) {
        int4 qB0, qB1, qB2, qB3;
        bool more = (b + 1 < nb);
        if (more) {
            qB0 = xp[(size_t)t0 * 16]; qB1 = xp[(size_t)t1 * 16];
            qB2 = xp[(size_t)t2 * 16]; qB3 = xp[(size_t)t3 * 16];
            int p = e + 8;
            t0 = col[min(p, last)];     t1 = col[min(p + 1, last)];
            t2 = col[min(p + 2, last)]; t3 = col[min(p + 3, last)];
        }
        proc(qA0); proc(qA1); proc(qA2); proc(qA3);
        if (more) { qA0 = qB0; qA1 = qB1; qA2 = qB2; qA3 = qB3; }
        e += 4;
    }
    for (e = r0 + nb * 4; e < r1; ++e)
        proc(xp[(size_t)col[e] * 16]);

    float inv = 1.f / ssum;               // self loop guarantees ssum > 0
    const float* bp = (isv ? biasv : biasm) + s * 8;
    float4 b0 = *(const float4*)bp, b1 = *(const float4*)(bp + 4);
    float r00 = elu1(fmaf(ac0, inv, b0.x));
    float r01 = elu1(fmaf(ac1, inv, b0.y));
    float r02 = elu1(fmaf(ac2, inv, b0.z));
    float r03 = elu1(fmaf(ac3, inv, b0.w));
    float r04 = elu1(fmaf(ac4, inv, b1.x));
    float r05 = elu1(fmaf(ac5, inv, b1.y));
    float r06 = elu1(fmaf(ac6, inv, b1.z));
    float r07 = elu1(fmaf(ac7, inv, b1.w));
    if (HOUT) {
        __half* op = (__half*)(isv ? outv : outm) + (size_t)node * 64 + s * 8;
        h2 p0 = {(_Float16)r00, (_Float16)r01}, p1 = {(_Float16)r02, (_Float16)r03};
        h2 p2 = {(_Float16)r04, (_Float16)r05}, p3 = {(_Float16)r06, (_Float16)r07};
        uint4 pk = {*(unsigned*)&p0, *(unsigned*)&p1, *(unsigned*)&p2, *(unsigned*)&p3};
        *(uint4*)op = pk;
    } else {
        float* op = (float*)(isv ? outv : outm) + (size_t)node * 64 + s * 8;
        float4 r0v = {r00, r01, r02, r03};
        float4 r1v = {r04, r05, r06, r07};
        *(float4*)op = r0v;
        *(float4*)(op + 4) = r1v;
    }
}

// ---- reparameterize + segment-mean-pool (batch is sorted) ------------------
// One wave per 16 nodes; per-wave segment accumulation => ~1-2 atomics per
// (graph,lane) instead of per-node scattering (R8 lesson).

__global__ void k_zpool(const float* __restrict__ mean, const float* __restrict__ logvar,
                        const float* __restrict__ eps, const int* __restrict__ batch,
                        float* __restrict__ zsum, int n) {
    int wave = blockIdx.x * 4 + (threadIdx.x >> 6);
    int lane = threadIdx.x & 63;
    int n0 = wave * 16;
    if (n0 >= n) return;
    int n1 = min(n0 + 16, n);
    float acc = 0.f;
    int gcur = -1;
    for (int nd = n0; nd < n1; ++nd) {
        int g = batch[nd];
        if (g != gcur) {
            if (gcur >= 0) atomicAdd(&zsum[gcur * 64 + lane], acc);
            gcur = g; acc = 0.f;
        }
        size_t o = (size_t)nd * 64 + lane;
        acc += fmaf(eps[o], __expf(0.5f * logvar[o]), mean[o]);
    }
    if (gcur >= 0) atomicAdd(&zsum[gcur * 64 + lane], acc);
}

// ---- FC head: block per graph (graph size via binary search on sorted batch)

__global__ void k_fchead(const float* __restrict__ zsum, const int* __restrict__ batch,
                         int N,
                         const float* __restrict__ fc1W, const float* __restrict__ fc1b,
                         const float* __restrict__ fc2W, const float* __restrict__ fc2b,
                         float* __restrict__ out) {
    __shared__ float zg[64];
    __shared__ float h1[128];
    __shared__ float lg[2];
    __shared__ int bnd[2];
    int g = blockIdx.x;
    int t = threadIdx.x;
    if (t < 2) {                 // t=0: lower_bound(g), t=1: lower_bound(g+1)
        int tgt = g + t, lo = 0, hi = N;
        while (lo < hi) {
            int m = (lo + hi) >> 1;
            if (batch[m] < tgt) lo = m + 1; else hi = m;
        }
        bnd[t] = lo;
    }
    __syncthreads();
    float cntg = (float)(bnd[1] - bnd[0]);
    if (t < 64) zg[t] = zsum[g * 64 + t] / cntg;
    __syncthreads();
    float h = fc1b[t];
#pragma unroll
    for (int k = 0; k < 64; ++k) h = fmaf(zg[k], fc1W[t * 64 + k], h);
    h1[t] = fmaxf(h, 0.f);
    __syncthreads();
    if (t < 2) {
        float l = fc2b[t];
        for (int k = 0; k < 128; ++k) l = fmaf(h1[k], fc2W[t * 128 + k], l);
        lg[t] = l;
    }
    __syncthreads();
    if (t == 0) {
        float mx = fmaxf(lg[0], lg[1]);
        float lse = mx + logf(expf(lg[0] - mx) + expf(lg[1] - mx));
        out[g * 2 + 0] = lg[0] - lse;
        out[g * 2 + 1] = lg[1] - lse;
    }
}

// ---------------------------------------------------------------------------

extern "C" void kernel_launch(void* const* d_in, const int* in_sizes, int n_in,
                              void* d_out, int out_size, void* d_ws, size_t ws_size,
                              hipStream_t stream) {
    const float* x     = (const float*)d_in[0];
    const float* eps   = (const float*)d_in[1];
    const int*   eidx  = (const int*)d_in[2];
    const int*   batch = (const int*)d_in[3];
    const float* m0_Wl = (const float*)d_in[4];
    const float* m0_bl = (const float*)d_in[5];
    const float* m0_Wr = (const float*)d_in[6];
    const float* m0_br = (const float*)d_in[7];
    const float* m0_att = (const float*)d_in[8];
    const float* m0_bias = (const float*)d_in[9];
    const float* v0_Wl = (const float*)d_in[10];
    const float* v0_bl = (const float*)d_in[11];
    const float* v0_Wr = (const float*)d_in[12];
    const float* v0_br = (const float*)d_in[13];
    const float* v0_att = (const float*)d_in[14];
    const float* v0_bias = (const float*)d_in[15];
    const float* m_Wl = (const float*)d_in[16];
    const float* m_bl = (const float*)d_in[17];
    const float* m_Wr = (const float*)d_in[18];
    const float* m_br = (const float*)d_in[19];
    const float* m_att = (const float*)d_in[20];
    const float* m_bias = (const float*)d_in[21];
    const float* v_Wl = (const float*)d_in[22];
    const float* v_bl = (const float*)d_in[23];
    const float* v_Wr = (const float*)d_in[24];
    const float* v_br = (const float*)d_in[25];
    const float* v_att = (const float*)d_in[26];
    const float* v_bias = (const float*)d_in[27];
    const float* fc1W = (const float*)d_in[28];
    const float* fc1b = (const float*)d_in[29];
    const float* fc2W = (const float*)d_in[30];
    const float* fc2b = (const float*)d_in[31];

    const int N = in_sizes[1] / 64;       // eps is [N,64]
    const int E = in_sizes[2] / 2;        // edge_index is [2,E]
    const int G = (out_size - N * 128) / 2;
    const int nbk = (N + (1 << BSH) - 1) >> BSH;   // buckets (<=1024)
    const int nsb = (N + SNB - 1) / SNB;           // degree-sort blocks
    const int* srcp = eidx;
    const int* dstp = eidx + E;

    char* wsb = (char*)d_ws;
    size_t off = 0;
    auto carve = [&](size_t bytes) -> void* {
        void* p = wsb + off;
        off += (bytes + 255) & ~(size_t)255;
        return p;
    };
    int*    rowptr   = (int*)carve((size_t)(N + 1) * sizeof(int));
    int*    col      = (int*)carve((size_t)E * sizeof(int));
    int*    pairs    = (int*)carve((size_t)E * sizeof(int));
    int*    bcnt     = (int*)carve((size_t)(nbk + 1) * sizeof(int));
    int*    boff     = (int*)carve((size_t)(nbk + 1) * sizeof(int));
    int*    bfill    = (int*)carve((size_t)nbk * sizeof(int));
    int*    nodeof   = (int*)carve((size_t)N * sizeof(int));
    int*    bin_cnt  = (int*)carve(256 * sizeof(int));
    int*    bin_off  = (int*)carve(256 * sizeof(int));
    int*    blk_base = (int*)carve((size_t)nsb * 256 * sizeof(int));
    __half* xlb      = (__half*)carve((size_t)N * 128 * sizeof(__half));
    __half* xrb      = (__half*)carve((size_t)N * 128 * sizeof(__half));
    __half* meanh    = (__half*)carve((size_t)N * 64 * sizeof(__half));
    __half* logvarh  = (__half*)carve((size_t)N * 64 * sizeof(__half));
    float*  zsum     = (float*)carve((size_t)G * 64 * sizeof(float));
    (void)ws_size;

    float* out_logits = (float*)d_out;
    float* mean_buf   = out_logits + (size_t)G * 2;
    float* logvar_buf = mean_buf + (size_t)N * 64;

    const int agrid = (N * 16 + 255) / 256;
    const int tgrid7 = (N * 32 + 255) / 256;
    const int ntiles = (N + 15) / 16;
    const int mgrid = (ntiles + 15) / 16;          // ~4 tiles per wave (W amortized)
    const int zgrid = ((N + 15) / 16 + 3) / 4;     // one wave per 16 nodes

    // ---- CSR build (hierarchical binned) ----
    (void)hipMemsetAsync(bcnt, 0, (size_t)nbk * sizeof(int), stream);
    k_hist_bucket<<<256, 256, 0, stream>>>(dstp, E, bcnt, nbk);
    k_scan_buckets<<<1, 1024, 0, stream>>>(bcnt, nbk, boff, bfill, bin_cnt);
    k_binfill<<<(E + CHUNK - 1) / CHUNK, 256, 0, stream>>>(srcp, dstp, E, boff, bfill, pairs);
    k_bucket_csr<<<nbk, 256, 0, stream>>>(pairs, boff, rowptr, col, N, E);

    // ---- degree counting-sort (descending, hierarchical/locality-keeping) ----
    k_deg_hist<<<nsb, 256, 0, stream>>>(rowptr, N, bin_cnt, blk_base);
    k_scan256<<<1, 256, 0, stream>>>(bin_cnt, bin_off, zsum, G);

    // ---- level 0 (input dim 7, both branches fused; + folded deg_scatter) ----
    k_transform7<<<tgrid7, 256, 0, stream>>>(x, m0_Wl, m0_bl, m0_Wr, m0_br,
                                             v0_Wl, v0_bl, v0_Wr, v0_br, xlb, xrb, N,
                                             rowptr, bin_off, blk_base, nodeof, nsb);
    k_aggregate2<true><<<agrid, 256, 0, stream>>>(
        xlb, xrb, m0_att, v0_att, m0_bias, v0_bias,
        rowptr, col, nodeof, meanh, logvarh, N);

    // ---- levels 1..2 (hidden dim 64, fused dual-branch MFMA transforms) ----
    for (int l = 0; l < 2; ++l) {
        k_transform_mfma2<<<dim3(mgrid, 2), 256, 0, stream>>>(
            meanh, logvarh,
            m_Wl + (size_t)l * 4096, m_bl + l * 64, m_Wr + (size_t)l * 4096, m_br + l * 64,
            v_Wl + (size_t)l * 4096, v_bl + l * 64, v_Wr + (size_t)l * 4096, v_br + l * 64,
            xlb, xrb, N);
        if (l == 0)
            k_aggregate2<true><<<agrid, 256, 0, stream>>>(
                xlb, xrb, m_att + l * 64, v_att + l * 64, m_bias + l * 64, v_bias + l * 64,
                rowptr, col, nodeof, meanh, logvarh, N);
        else
            k_aggregate2<false><<<agrid, 256, 0, stream>>>(
                xlb, xrb, m_att + l * 64, v_att + l * 64, m_bias + l * 64, v_bias + l * 64,
                rowptr, col, nodeof, mean_buf, logvar_buf, N);
    }

    // ---- reparameterize + pool + FC head ----
    k_zpool<<<zgrid, 256, 0, stream>>>(mean_buf, logvar_buf, eps, batch, zsum, N);
    k_fchead<<<G, 128, 0, stream>>>(zsum, batch, N, fc1W, fc1b, fc2W, fc2b, out_logits);
}